// Round 1
// baseline (1796.374 us; speedup 1.0000x reference)
//
#include <hip/hip_runtime.h>
#include <stdint.h>

#define EPS 1e-5f

// ---------------- ws layout ----------------
// floats:
//  [0,4)      absmax {c1,c2,f1,f2}
//  [16,80)    c1 sum     [80,144)  c1 ssq   [144,208) c1 scale  [208,272) c1 shift
//  [272,400)  c2 sum     [400,528) c2 ssq   [528,656) c2 scale  [656,784) c2 shift
//  [784,1296) fc scale   [1296,1808) fc shift
// bytes:
//  QC1 @ 8192 (1600 B), QC2 @ 9792 (204800 B), QF1 @ 214592 (1048576 B),
//  QF2 @ 1263168 (5120 B)
//  ACT @ 1310720: A = 18874368 floats (conv1out / conv2out / fc1out)
//                 B = 4718592 floats  (pool1 / pool2)
static const size_t QC1_OFF = 8192;
static const size_t QC2_OFF = QC1_OFF + 1600;
static const size_t QF1_OFF = QC2_OFF + 204800;
static const size_t QF2_OFF = QF1_OFF + 1048576;
static const size_t ACT_OFF = 1310720;              // bytes
static const size_t A_FOFF  = ACT_OFF / 4;          // float index
static const size_t A_SIZE  = 18874368;             // 512*64*24*24
static const size_t B_FOFF  = A_FOFF + A_SIZE;

__global__ void k_zero(float* p, int n) {
    int i = blockIdx.x * blockDim.x + threadIdx.x;
    if (i < n) p[i] = 0.f;
}

__global__ void k_absmax(const float* __restrict__ w, int n, unsigned* out) {
    float m = 0.f;
    for (int i = blockIdx.x * blockDim.x + threadIdx.x; i < n; i += gridDim.x * blockDim.x)
        m = fmaxf(m, fabsf(w[i]));
    #pragma unroll
    for (int o = 32; o; o >>= 1) m = fmaxf(m, __shfl_down(m, o));
    if ((threadIdx.x & 63) == 0) atomicMax(out, __float_as_uint(m));
}

__global__ void k_quant(const float* __restrict__ w, int n,
                        const float* __restrict__ absmax, int8_t* __restrict__ q) {
    float t = 0.05f * absmax[0];
    for (int i = blockIdx.x * blockDim.x + threadIdx.x; i < n; i += gridDim.x * blockDim.x) {
        float v = w[i];
        q[i] = (int8_t)((v > t) - (v < -t));
    }
}

// conv1: x[512,1,28,28] -> out[512,64,24,24]
__global__ void k_conv1(const float* __restrict__ x, const int8_t* __restrict__ q,
                        const float* __restrict__ bias, float* __restrict__ out) {
    int idx = blockIdx.x * 256 + threadIdx.x;          // 18874368 total
    int ow = idx % 24; int t = idx / 24;
    int oh = t % 24;   t /= 24;
    int c  = t & 63;   int b = t >> 6;
    const float* xp = x + (size_t)b * 784 + oh * 28 + ow;
    const int8_t* qp = q + c * 25;
    float acc = bias[c];
    #pragma unroll
    for (int kh = 0; kh < 5; ++kh)
        #pragma unroll
        for (int kw = 0; kw < 5; ++kw)
            acc = fmaf((float)qp[kh * 5 + kw], xp[kh * 28 + kw], acc);
    out[idx] = acc;
}

// per-channel sum/sumsq over [B,C,HW]; blockIdx.x = c, blockIdx.y = chunk
__global__ void k_stats(const float* __restrict__ x, int C, int HW, int B,
                        float* __restrict__ sum, float* __restrict__ ssq) {
    int c = blockIdx.x;
    int total = B * HW;
    float s = 0.f, s2 = 0.f;
    for (int i = blockIdx.y * blockDim.x + threadIdx.x; i < total; i += gridDim.y * blockDim.x) {
        int b = i / HW; int hw = i - b * HW;
        float v = x[((size_t)b * C + c) * HW + hw];
        s += v; s2 += v * v;
    }
    #pragma unroll
    for (int o = 32; o; o >>= 1) { s += __shfl_down(s, o); s2 += __shfl_down(s2, o); }
    if ((threadIdx.x & 63) == 0) { atomicAdd(&sum[c], s); atomicAdd(&ssq[c], s2); }
}

__global__ void k_finalize(const float* __restrict__ sum, const float* __restrict__ ssq,
                           const float* __restrict__ g, const float* __restrict__ bt,
                           float* __restrict__ scale, float* __restrict__ shift,
                           int C, float invN) {
    int c = blockIdx.x * blockDim.x + threadIdx.x;
    if (c >= C) return;
    float mean = sum[c] * invN;
    float var  = ssq[c] * invN - mean * mean;
    float sc   = g[c] * rsqrtf(var + EPS);
    scale[c] = sc;
    shift[c] = bt[c] - mean * sc;
}

// bn + relu + 2x2 maxpool: x[B,C,H,W] -> out[B,C,H/2,W/2]
__global__ void k_bnpool(const float* __restrict__ x, const float* __restrict__ scale,
                         const float* __restrict__ shift, float* __restrict__ out,
                         int C, int H, int W, int n) {
    int idx = blockIdx.x * blockDim.x + threadIdx.x;
    if (idx >= n) return;
    int Wo = W >> 1, Ho = H >> 1;
    int ow = idx % Wo; int t = idx / Wo;
    int oh = t % Ho;   t /= Ho;
    int c  = t % C;    int b = t / C;
    const float* xp = x + (((size_t)b * C + c) * H + oh * 2) * W + ow * 2;
    float sc = scale[c], sh = shift[c];
    float v0 = fmaxf(0.f, fmaf(xp[0],     sc, sh));
    float v1 = fmaxf(0.f, fmaf(xp[1],     sc, sh));
    float v2 = fmaxf(0.f, fmaf(xp[W],     sc, sh));
    float v3 = fmaxf(0.f, fmaf(xp[W + 1], sc, sh));
    out[idx] = fmaxf(fmaxf(v0, v1), fmaxf(v2, v3));
}

// conv2: pool1[512,64,12,12] -> out[512,128,8,8]
__global__ void k_conv2(const float* __restrict__ x, const int8_t* __restrict__ q,
                        const float* __restrict__ bias, float* __restrict__ out) {
    int idx = blockIdx.x * 256 + threadIdx.x;          // 4194304 total
    int ow = idx & 7;  int t = idx >> 3;
    int oh = t & 7;    t >>= 3;
    int c  = t & 127;  int b = t >> 7;
    const float* xb = x + (size_t)b * 64 * 144;
    const int8_t* qp = q + c * 1600;
    float acc = bias[c];
    for (int ci = 0; ci < 64; ++ci) {
        const float* xc = xb + ci * 144 + oh * 12 + ow;
        const int8_t* qc = qp + ci * 25;
        #pragma unroll
        for (int kh = 0; kh < 5; ++kh)
            #pragma unroll
            for (int kw = 0; kw < 5; ++kw)
                acc = fmaf((float)qc[kh * 5 + kw], xc[kh * 12 + kw], acc);
    }
    out[idx] = acc;
}

// fc1: x[512,2048] @ qT[2048,512] + b -> out[512,512]
__global__ void k_fc1(const float* __restrict__ x, const int8_t* __restrict__ q,
                      const float* __restrict__ bias, float* __restrict__ out) {
    int idx = blockIdx.x * 256 + threadIdx.x;          // 262144 total
    int f = idx & 511; int b = idx >> 9;
    const float* xp = x + (size_t)b * 2048;
    const int8_t* qp = q + (size_t)f * 2048;
    float acc = bias[f];
    for (int k = 0; k < 2048; ++k)
        acc = fmaf((float)qp[k], xp[k], acc);
    out[idx] = acc;
}

// fc bn stats over batch (axis 0): one thread per feature, coalesced column reads
__global__ void k_fcstats(const float* __restrict__ x, const float* __restrict__ g,
                          const float* __restrict__ bt,
                          float* __restrict__ scale, float* __restrict__ shift) {
    int f = blockIdx.x * blockDim.x + threadIdx.x;
    if (f >= 512) return;
    float s = 0.f, s2 = 0.f;
    for (int b = 0; b < 512; ++b) {
        float v = x[(size_t)b * 512 + f];
        s += v; s2 += v * v;
    }
    float mean = s * (1.f / 512.f);
    float var  = s2 * (1.f / 512.f) - mean * mean;
    float sc   = g[f] * rsqrtf(var + EPS);
    scale[f] = sc;
    shift[f] = bt[f] - mean * sc;
}

__global__ void k_fcbn(float* __restrict__ x, const float* __restrict__ scale,
                       const float* __restrict__ shift) {
    int i = blockIdx.x * 256 + threadIdx.x;            // 262144 total
    int f = i & 511;
    x[i] = fmaxf(0.f, fmaf(x[i], scale[f], shift[f]));
}

// fc2: x[512,512] @ qT[512,10] + b -> out[512,10]
__global__ void k_fc2(const float* __restrict__ x, const int8_t* __restrict__ q,
                      const float* __restrict__ bias, float* __restrict__ out) {
    int idx = blockIdx.x * blockDim.x + threadIdx.x;
    if (idx >= 5120) return;
    int j = idx % 10; int b = idx / 10;
    const float* xp = x + (size_t)b * 512;
    const int8_t* qp = q + j * 512;
    float acc = bias[j];
    for (int k = 0; k < 512; ++k)
        acc = fmaf((float)qp[k], xp[k], acc);
    out[idx] = acc;
}

extern "C" void kernel_launch(void* const* d_in, const int* in_sizes, int n_in,
                              void* d_out, int out_size, void* d_ws, size_t ws_size,
                              hipStream_t stream) {
    const float* x       = (const float*)d_in[0];
    const float* conv1_w = (const float*)d_in[1];
    const float* conv1_b = (const float*)d_in[2];
    const float* bn1_g   = (const float*)d_in[3];
    const float* bn1_b   = (const float*)d_in[4];
    const float* conv2_w = (const float*)d_in[5];
    const float* conv2_b = (const float*)d_in[6];
    const float* bn2_g   = (const float*)d_in[7];
    const float* bn2_b   = (const float*)d_in[8];
    const float* fc1_w   = (const float*)d_in[9];
    const float* fc1_b   = (const float*)d_in[10];
    const float* bn3_g   = (const float*)d_in[11];
    const float* bn3_b   = (const float*)d_in[12];
    const float* fc2_w   = (const float*)d_in[13];
    const float* fc2_b   = (const float*)d_in[14];

    float*  wsf = (float*)d_ws;
    int8_t* ws8 = (int8_t*)d_ws;

    float* c1_sum = wsf + 16,  * c1_ssq = wsf + 80;
    float* c1_sc  = wsf + 144, * c1_sh  = wsf + 208;
    float* c2_sum = wsf + 272, * c2_ssq = wsf + 400;
    float* c2_sc  = wsf + 528, * c2_sh  = wsf + 656;
    float* f_sc   = wsf + 784, * f_sh   = wsf + 1296;

    int8_t* qc1 = ws8 + QC1_OFF;
    int8_t* qc2 = ws8 + QC2_OFF;
    int8_t* qf1 = ws8 + QF1_OFF;
    int8_t* qf2 = ws8 + QF2_OFF;

    float* A  = wsf + A_FOFF;   // conv1out -> conv2out -> fc1out
    float* Bb = wsf + B_FOFF;   // pool1 -> pool2

    // 1) zero stats/absmax region
    k_zero<<<8, 256, 0, stream>>>(wsf, 2048);

    // 2) absmax per weight tensor
    k_absmax<<<8,   256, 0, stream>>>(conv1_w, 1600,    (unsigned*)(wsf + 0));
    k_absmax<<<64,  256, 0, stream>>>(conv2_w, 204800,  (unsigned*)(wsf + 1));
    k_absmax<<<256, 256, 0, stream>>>(fc1_w,   1048576, (unsigned*)(wsf + 2));
    k_absmax<<<8,   256, 0, stream>>>(fc2_w,   5120,    (unsigned*)(wsf + 3));

    // 3) ternary quantize
    k_quant<<<8,   256, 0, stream>>>(conv1_w, 1600,    wsf + 0, qc1);
    k_quant<<<128, 256, 0, stream>>>(conv2_w, 204800,  wsf + 1, qc2);
    k_quant<<<512, 256, 0, stream>>>(fc1_w,   1048576, wsf + 2, qf1);
    k_quant<<<8,   256, 0, stream>>>(fc2_w,   5120,    wsf + 3, qf2);

    // 4) conv1 -> A [512,64,24,24]
    k_conv1<<<73728, 256, 0, stream>>>(x, qc1, conv1_b, A);

    // 5) bn1 stats + finalize
    { dim3 g(64, 36); k_stats<<<g, 256, 0, stream>>>(A, 64, 576, 512, c1_sum, c1_ssq); }
    k_finalize<<<1, 64, 0, stream>>>(c1_sum, c1_ssq, bn1_g, bn1_b, c1_sc, c1_sh, 64,
                                     1.f / 294912.f);

    // 6) bn+relu+pool -> B [512,64,12,12]
    k_bnpool<<<18432, 256, 0, stream>>>(A, c1_sc, c1_sh, Bb, 64, 24, 24, 4718592);

    // 7) conv2 -> A [512,128,8,8]
    k_conv2<<<16384, 256, 0, stream>>>(Bb, qc2, conv2_b, A);

    // 8) bn2 stats + finalize
    { dim3 g(128, 8); k_stats<<<g, 256, 0, stream>>>(A, 128, 64, 512, c2_sum, c2_ssq); }
    k_finalize<<<1, 128, 0, stream>>>(c2_sum, c2_ssq, bn2_g, bn2_b, c2_sc, c2_sh, 128,
                                      1.f / 32768.f);

    // 9) bn+relu+pool -> B [512,128,4,4] (= flat [512,2048])
    k_bnpool<<<4096, 256, 0, stream>>>(A, c2_sc, c2_sh, Bb, 128, 8, 8, 1048576);

    // 10) fc1 -> A [512,512]
    k_fc1<<<1024, 256, 0, stream>>>(Bb, qf1, fc1_b, A);

    // 11) bn3 stats (+scale/shift), in-place bn+relu
    k_fcstats<<<2, 256, 0, stream>>>(A, bn3_g, bn3_b, f_sc, f_sh);
    k_fcbn<<<1024, 256, 0, stream>>>(A, f_sc, f_sh);

    // 12) fc2 -> d_out [512,10]
    k_fc2<<<20, 256, 0, stream>>>(A, qf2, fc2_b, (float*)d_out);
}

// Round 2
// 945.607 us; speedup vs baseline: 1.8997x; 1.8997x over previous
//
#include <hip/hip_runtime.h>
#include <stdint.h>

#define EPS 1e-5f

// ---------------- ws float layout ----------------
//  [0,4)     absmax {c1,c2,f1,f2}
//  16/80/144/208    c1 sum/ssq/scale/shift (64 each)
//  272/400/528/656  c2 sum/ssq/scale/shift (128 each)
//  784 fc scale(512) 1296 fc shift(512)
//  W1F  = 2048    : conv1 weights float [c][25]            (1600)
//  W2F  = 4096    : conv2 weights float [ci][c][25]        (204800)
//  WF2F = 212992  : fc2 weights float [j][512]             (5120)
//  A_F  = 262144  : A (18874368) conv1out / conv2out / fc1out
//  B_F  = 19136512: B (4718592)  pool1 / pool2
//  WF1T = B_F + 1048576 : fc1 weights float [k=2048][f=512] (1048576)
//         (written AFTER conv2, when pool1 is dead; pool2 only uses first
//          1048576 floats of B, so no overlap)
static const size_t W1F  = 2048;
static const size_t W2F  = 4096;
static const size_t WF2F = 212992;
static const size_t A_F  = 262144;
static const size_t B_F  = 19136512;
static const size_t WF1T = B_F + 1048576;

__global__ void k_zero(float* p, int n) {
    int i = blockIdx.x * blockDim.x + threadIdx.x;
    if (i < n) p[i] = 0.f;
}

// 4 absmax reductions in one launch; block ranges per segment
__global__ void k_absmax4(const float* __restrict__ w0, int n0,
                          const float* __restrict__ w1, int n1,
                          const float* __restrict__ w2, int n2,
                          const float* __restrict__ w3, int n3,
                          float* outv) {
    int blk = blockIdx.x;
    const float* w; int n; unsigned* out; int nb; int bi;
    if (blk < 1)       { w = w0; n = n0; out = (unsigned*)(outv + 0); nb = 1;  bi = blk;      }
    else if (blk < 17) { w = w1; n = n1; out = (unsigned*)(outv + 1); nb = 16; bi = blk - 1;  }
    else if (blk < 81) { w = w2; n = n2; out = (unsigned*)(outv + 2); nb = 64; bi = blk - 17; }
    else               { w = w3; n = n3; out = (unsigned*)(outv + 3); nb = 1;  bi = blk - 81; }
    float m = 0.f;
    for (int i = bi * 256 + threadIdx.x; i < n; i += nb * 256)
        m = fmaxf(m, fabsf(w[i]));
    #pragma unroll
    for (int o = 32; o; o >>= 1) m = fmaxf(m, __shfl_down(m, o));
    if ((threadIdx.x & 63) == 0) atomicMax(out, __float_as_uint(m));
}

// quantize conv1 (straight), conv2 (transposed to [ci][c][k]), fc2 (straight)
__global__ void k_quantE(const float* __restrict__ c1w, const float* __restrict__ c2w,
                         const float* __restrict__ f2w, const float* __restrict__ am,
                         float* __restrict__ w1, float* __restrict__ w2,
                         float* __restrict__ wf2) {
    int blk = blockIdx.x;
    if (blk < 1) {                       // conv1: 1600
        float t = 0.05f * am[0];
        for (int i = threadIdx.x; i < 1600; i += 256) {
            float v = c1w[i];
            w1[i] = (float)((v > t) - (v < -t));
        }
    } else if (blk < 101) {              // conv2: 204800 = 100 * 2048
        float t = 0.05f * am[1];
        int base = (blk - 1) * 2048;
        #pragma unroll
        for (int j = 0; j < 8; ++j) {
            int i = base + j * 256 + threadIdx.x;
            float v = c2w[i];
            float q = (float)((v > t) - (v < -t));
            int c = i / 1600; int r = i - c * 1600;
            int ci = r / 25;  int k = r - ci * 25;
            w2[(ci * 128 + c) * 25 + k] = q;
        }
    } else {                             // fc2: 5120
        float t = 0.05f * am[3];
        for (int i = threadIdx.x; i < 5120; i += 256) {
            float v = f2w[i];
            wf2[i] = (float)((v > t) - (v < -t));
        }
    }
}

// fc1 quantize, transposed to [k][f]; runs AFTER conv2 (writes into dead pool1)
__global__ void k_quantF1(const float* __restrict__ w, const float* __restrict__ am,
                          float* __restrict__ wt) {
    float t = 0.05f * am[2];
    int i = blockIdx.x * 256 + threadIdx.x;        // 1048576 total
    float v = w[i];
    float q = (float)((v > t) - (v < -t));
    int f = i >> 11, k = i & 2047;
    wt[k * 512 + f] = q;
}

// conv1: x[512,1,28,28] -> out[512,64,24,24]; block per image, LDS-staged input,
// weight loads are loop-uniform -> scalar s_load
__global__ __launch_bounds__(192) void k_conv1(const float* __restrict__ x,
                                               const float* __restrict__ w,
                                               float* __restrict__ out) {
    __shared__ float xs[784];
    int b = blockIdx.x;
    const float4* xim = (const float4*)(x + (size_t)b * 784);
    for (int i = threadIdx.x; i < 196; i += 192) ((float4*)xs)[i] = xim[i];
    __syncthreads();
    float* ob = out + (size_t)b * 36864;
    for (int pass = 0; pass < 3; ++pass) {
        int sp = pass * 192 + threadIdx.x;
        int oh = sp / 24, ow = sp - oh * 24;
        float win[25];
        #pragma unroll
        for (int kh = 0; kh < 5; ++kh)
            #pragma unroll
            for (int kw = 0; kw < 5; ++kw)
                win[kh * 5 + kw] = xs[(oh + kh) * 28 + ow + kw];
        for (int c = 0; c < 64; ++c) {
            const float* wc = w + c * 25;
            float acc = 0.f;
            #pragma unroll
            for (int k = 0; k < 25; ++k) acc = fmaf(wc[k], win[k], acc);
            ob[c * 576 + sp] = acc;
        }
    }
}

// conv2: pool1[512,64,12,12] -> out[512,128,8,8]; block per image,
// thread = (spatial 64, channel-group 32); window in regs reused over 32 ch;
// weights wave-uniform (readfirstlane) -> s_load
__global__ __launch_bounds__(256) void k_conv2(const float* __restrict__ x,
                                               const float* __restrict__ w,
                                               float* __restrict__ out) {
    __shared__ float xs[9216];
    int b = blockIdx.x;
    const float4* xim = (const float4*)(x + (size_t)b * 9216);
    for (int i = threadIdx.x; i < 2304; i += 256) ((float4*)xs)[i] = xim[i];
    __syncthreads();
    int sp = threadIdx.x & 63;
    int oh = sp >> 3, ow = sp & 7;
    int cbase = __builtin_amdgcn_readfirstlane((int)(threadIdx.x >> 6)) * 32;
    float acc[32];
    #pragma unroll
    for (int c = 0; c < 32; ++c) acc[c] = 0.f;
    for (int ci = 0; ci < 64; ++ci) {
        float win[25];
        const float* xc = xs + ci * 144 + oh * 12 + ow;
        #pragma unroll
        for (int kh = 0; kh < 5; ++kh)
            #pragma unroll
            for (int kw = 0; kw < 5; ++kw)
                win[kh * 5 + kw] = xc[kh * 12 + kw];
        const float* wp = w + (ci * 128 + cbase) * 25;
        #pragma unroll
        for (int c = 0; c < 32; ++c) {
            #pragma unroll
            for (int k = 0; k < 25; ++k)
                acc[c] = fmaf(wp[c * 25 + k], win[k], acc[c]);
        }
    }
    float* ob = out + ((size_t)b * 128 + cbase) * 64 + sp;
    #pragma unroll
    for (int c = 0; c < 32; ++c) ob[c * 64] = acc[c];
}

// per-channel sum/sumsq over [B,C,HW]
__global__ void k_stats(const float* __restrict__ x, int C, int HW, int B,
                        float* __restrict__ sum, float* __restrict__ ssq) {
    int c = blockIdx.x;
    int total = B * HW;
    float s = 0.f, s2 = 0.f;
    for (int i = blockIdx.y * blockDim.x + threadIdx.x; i < total; i += gridDim.y * blockDim.x) {
        int b = i / HW; int hw = i - b * HW;
        float v = x[((size_t)b * C + c) * HW + hw];
        s += v; s2 += v * v;
    }
    #pragma unroll
    for (int o = 32; o; o >>= 1) { s += __shfl_down(s, o); s2 += __shfl_down(s2, o); }
    if ((threadIdx.x & 63) == 0) { atomicAdd(&sum[c], s); atomicAdd(&ssq[c], s2); }
}

__global__ void k_finalize(const float* __restrict__ sum, const float* __restrict__ ssq,
                           const float* __restrict__ g, const float* __restrict__ bt,
                           float* __restrict__ scale, float* __restrict__ shift,
                           int C, float invN) {
    int c = blockIdx.x * blockDim.x + threadIdx.x;
    if (c >= C) return;
    float mean = sum[c] * invN;
    float var  = ssq[c] * invN - mean * mean;
    float sc   = g[c] * rsqrtf(var + EPS);
    scale[c] = sc;
    shift[c] = bt[c] - mean * sc;
}

// bn + relu + 2x2 maxpool
__global__ void k_bnpool(const float* __restrict__ x, const float* __restrict__ scale,
                         const float* __restrict__ shift, float* __restrict__ out,
                         int C, int H, int W, int n) {
    int idx = blockIdx.x * blockDim.x + threadIdx.x;
    if (idx >= n) return;
    int Wo = W >> 1, Ho = H >> 1;
    int ow = idx % Wo; int t = idx / Wo;
    int oh = t % Ho;   t /= Ho;
    int c  = t % C;    int b = t / C;
    const float* xp = x + (((size_t)b * C + c) * H + oh * 2) * W + ow * 2;
    float sc = scale[c], sh = shift[c];
    float v0 = fmaxf(0.f, fmaf(xp[0],     sc, sh));
    float v1 = fmaxf(0.f, fmaf(xp[1],     sc, sh));
    float v2 = fmaxf(0.f, fmaf(xp[W],     sc, sh));
    float v3 = fmaxf(0.f, fmaf(xp[W + 1], sc, sh));
    out[idx] = fmaxf(fmaxf(v0, v1), fmaxf(v2, v3));
}

// fc1: pool2[512,2048] @ wt[2048,512] -> out[512,512]; 4 batches/thread,
// coalesced weight loads, scalar x loads (bias absorbed by bn3)
__global__ __launch_bounds__(256) void k_fc1(const float* __restrict__ x,
                                             const float* __restrict__ wt,
                                             float* __restrict__ out) {
    int idx = blockIdx.x * 256 + threadIdx.x;      // 65536
    int f = idx & 511;
    int bg = __builtin_amdgcn_readfirstlane(idx >> 9);  // uniform per wave
    const float* x0 = x + (size_t)bg * 4 * 2048;
    float a0 = 0.f, a1 = 0.f, a2 = 0.f, a3 = 0.f;
    #pragma unroll 8
    for (int k = 0; k < 2048; ++k) {
        float wv = wt[k * 512 + f];
        a0 = fmaf(wv, x0[k],        a0);
        a1 = fmaf(wv, x0[2048 + k], a1);
        a2 = fmaf(wv, x0[4096 + k], a2);
        a3 = fmaf(wv, x0[6144 + k], a3);
    }
    float* o = out + (size_t)bg * 4 * 512 + f;
    o[0] = a0; o[512] = a1; o[1024] = a2; o[1536] = a3;
}

__global__ void k_fcstats(const float* __restrict__ x, const float* __restrict__ g,
                          const float* __restrict__ bt,
                          float* __restrict__ scale, float* __restrict__ shift) {
    int f = blockIdx.x * blockDim.x + threadIdx.x;
    if (f >= 512) return;
    float s = 0.f, s2 = 0.f;
    for (int b = 0; b < 512; ++b) {
        float v = x[(size_t)b * 512 + f];
        s += v; s2 += v * v;
    }
    float mean = s * (1.f / 512.f);
    float var  = s2 * (1.f / 512.f) - mean * mean;
    float sc   = g[f] * rsqrtf(var + EPS);
    scale[f] = sc;
    shift[f] = bt[f] - mean * sc;
}

__global__ void k_fcbn(float* __restrict__ x, const float* __restrict__ scale,
                       const float* __restrict__ shift) {
    int i = blockIdx.x * 256 + threadIdx.x;        // 262144
    int f = i & 511;
    x[i] = fmaxf(0.f, fmaf(x[i], scale[f], shift[f]));
}

// fc2: x[512,512] @ w[10,512]^T + b -> out[512,10]
__global__ void k_fc2(const float* __restrict__ x, const float* __restrict__ w,
                      const float* __restrict__ bias, float* __restrict__ out) {
    int idx = blockIdx.x * blockDim.x + threadIdx.x;
    if (idx >= 5120) return;
    int j = idx % 10; int b = idx / 10;
    const float* xp = x + (size_t)b * 512;
    const float* wp = w + j * 512;
    float acc = bias[j];
    #pragma unroll 4
    for (int k = 0; k < 512; ++k) acc = fmaf(wp[k], xp[k], acc);
    out[idx] = acc;
}

extern "C" void kernel_launch(void* const* d_in, const int* in_sizes, int n_in,
                              void* d_out, int out_size, void* d_ws, size_t ws_size,
                              hipStream_t stream) {
    const float* x       = (const float*)d_in[0];
    const float* conv1_w = (const float*)d_in[1];
    const float* bn1_g   = (const float*)d_in[3];
    const float* bn1_b   = (const float*)d_in[4];
    const float* conv2_w = (const float*)d_in[5];
    const float* bn2_g   = (const float*)d_in[7];
    const float* bn2_b   = (const float*)d_in[8];
    const float* fc1_w   = (const float*)d_in[9];
    const float* bn3_g   = (const float*)d_in[11];
    const float* bn3_b   = (const float*)d_in[12];
    const float* fc2_w   = (const float*)d_in[13];
    const float* fc2_b   = (const float*)d_in[14];
    // conv1_b / conv2_b / fc1_b are mathematically absorbed by train-mode BN

    float* wsf = (float*)d_ws;

    float* c1_sum = wsf + 16,  * c1_ssq = wsf + 80;
    float* c1_sc  = wsf + 144, * c1_sh  = wsf + 208;
    float* c2_sum = wsf + 272, * c2_ssq = wsf + 400;
    float* c2_sc  = wsf + 528, * c2_sh  = wsf + 656;
    float* f_sc   = wsf + 784, * f_sh   = wsf + 1296;

    float* w1  = wsf + W1F;
    float* w2  = wsf + W2F;
    float* wf2 = wsf + WF2F;
    float* wt1 = wsf + WF1T;
    float* A   = wsf + A_F;
    float* Bb  = wsf + B_F;

    // stats/absmax zero
    k_zero<<<8, 256, 0, stream>>>(wsf, 2048);

    // absmax (all 4 tensors, one launch)
    k_absmax4<<<82, 256, 0, stream>>>(conv1_w, 1600, conv2_w, 204800,
                                      fc1_w, 1048576, fc2_w, 5120, wsf);

    // quantize conv1/conv2/fc2 to float (conv2 transposed to [ci][c][k])
    k_quantE<<<102, 256, 0, stream>>>(conv1_w, conv2_w, fc2_w, wsf, w1, w2, wf2);

    // conv1 -> A [512,64,24,24]
    k_conv1<<<512, 192, 0, stream>>>(x, w1, A);

    // bn1 stats + finalize
    { dim3 g(64, 36); k_stats<<<g, 256, 0, stream>>>(A, 64, 576, 512, c1_sum, c1_ssq); }
    k_finalize<<<1, 64, 0, stream>>>(c1_sum, c1_ssq, bn1_g, bn1_b, c1_sc, c1_sh, 64,
                                     1.f / 294912.f);

    // bn+relu+pool -> B [512,64,12,12]
    k_bnpool<<<18432, 256, 0, stream>>>(A, c1_sc, c1_sh, Bb, 64, 24, 24, 4718592);

    // conv2 -> A [512,128,8,8]
    k_conv2<<<512, 256, 0, stream>>>(Bb, w2, A);

    // fc1 weights (transposed), into dead pool1 region
    k_quantF1<<<4096, 256, 0, stream>>>(fc1_w, wsf, wt1);

    // bn2 stats + finalize
    { dim3 g(128, 8); k_stats<<<g, 256, 0, stream>>>(A, 128, 64, 512, c2_sum, c2_ssq); }
    k_finalize<<<1, 128, 0, stream>>>(c2_sum, c2_ssq, bn2_g, bn2_b, c2_sc, c2_sh, 128,
                                      1.f / 32768.f);

    // bn+relu+pool -> B [512,128,4,4] (= [512,2048])
    k_bnpool<<<4096, 256, 0, stream>>>(A, c2_sc, c2_sh, Bb, 128, 8, 8, 1048576);

    // fc1 -> A [512,512]
    k_fc1<<<256, 256, 0, stream>>>(Bb, wt1, A);

    // bn3 stats + in-place bn+relu
    k_fcstats<<<2, 256, 0, stream>>>(A, bn3_g, bn3_b, f_sc, f_sh);
    k_fcbn<<<1024, 256, 0, stream>>>(A, f_sc, f_sh);

    // fc2 -> d_out [512,10]
    k_fc2<<<20, 256, 0, stream>>>(A, wf2, fc2_b, (float*)d_out);
}

// Round 3
// 744.749 us; speedup vs baseline: 2.4121x; 1.2697x over previous
//
#include <hip/hip_runtime.h>
#include <stdint.h>

#define EPS 1e-5f

// ---------------- ws float layout ----------------
//  [0,4)     absmax {c1,c2,f1,f2}
//  16/80/144/208    c1 sum/ssq/scale/shift (64 each)
//  272/400/528/656  c2 sum/ssq/scale/shift (128 each)
//  784 fc scale(512) 1296 fc shift(512)
//  W1F  = 2048    : conv1 weights float [k=25][c=64]       (1600)
//  W2F  = 4096    : conv2 weights float [ci][c][25]        (204800)
//  WF2F = 212992  : fc2 weights float [j][512]             (5120)
//  A_F  = 262144  : A: conv2out [512,128,8,8] / fc1out [512,512]
//  B_F  = 19136512: B: pool1 [512,64,12,12] / pool2 [512,2048]
//  WF1T = B_F + 1048576 : fc1 weights float [k=2048][f=512] (1048576)
//         (written AFTER conv2, when pool1 is dead; pool2 only uses first
//          1048576 floats of B)
static const size_t W1F  = 2048;
static const size_t W2F  = 4096;
static const size_t WF2F = 212992;
static const size_t A_F  = 262144;
static const size_t B_F  = 19136512;
static const size_t WF1T = B_F + 1048576;

__global__ void k_zero(float* p, int n) {
    int i = blockIdx.x * blockDim.x + threadIdx.x;
    if (i < n) p[i] = 0.f;
}

// 4 absmax reductions in one launch
__global__ void k_absmax4(const float* __restrict__ w0, int n0,
                          const float* __restrict__ w1, int n1,
                          const float* __restrict__ w2, int n2,
                          const float* __restrict__ w3, int n3,
                          float* outv) {
    int blk = blockIdx.x;
    const float* w; int n; unsigned* out; int nb; int bi;
    if (blk < 1)       { w = w0; n = n0; out = (unsigned*)(outv + 0); nb = 1;  bi = blk;      }
    else if (blk < 17) { w = w1; n = n1; out = (unsigned*)(outv + 1); nb = 16; bi = blk - 1;  }
    else if (blk < 81) { w = w2; n = n2; out = (unsigned*)(outv + 2); nb = 64; bi = blk - 17; }
    else               { w = w3; n = n3; out = (unsigned*)(outv + 3); nb = 1;  bi = blk - 81; }
    float m = 0.f;
    for (int i = bi * 256 + threadIdx.x; i < n; i += nb * 256)
        m = fmaxf(m, fabsf(w[i]));
    #pragma unroll
    for (int o = 32; o; o >>= 1) m = fmaxf(m, __shfl_down(m, o));
    if ((threadIdx.x & 63) == 0) atomicMax(out, __float_as_uint(m));
}

// quantize: conv1 -> w1t [k=25][c=64]; conv2 -> w2 [ci][c][25]; fc2 straight
__global__ void k_quantE(const float* __restrict__ c1w, const float* __restrict__ c2w,
                         const float* __restrict__ f2w, const float* __restrict__ am,
                         float* __restrict__ w1t, float* __restrict__ w2,
                         float* __restrict__ wf2) {
    int blk = blockIdx.x;
    if (blk < 1) {                       // conv1: 1600, transpose to [k][c]
        float t = 0.05f * am[0];
        for (int i = threadIdx.x; i < 1600; i += 256) {
            float v = c1w[i];
            float q = (float)((v > t) - (v < -t));
            int c = i / 25, k = i - c * 25;
            w1t[k * 64 + c] = q;
        }
    } else if (blk < 101) {              // conv2: 204800 = 100 * 2048
        float t = 0.05f * am[1];
        int base = (blk - 1) * 2048;
        #pragma unroll
        for (int j = 0; j < 8; ++j) {
            int i = base + j * 256 + threadIdx.x;
            float v = c2w[i];
            float q = (float)((v > t) - (v < -t));
            int c = i / 1600; int r = i - c * 1600;
            int ci = r / 25;  int k = r - ci * 25;
            w2[(ci * 128 + c) * 25 + k] = q;
        }
    } else {                             // fc2: 5120
        float t = 0.05f * am[3];
        for (int i = threadIdx.x; i < 5120; i += 256) {
            float v = f2w[i];
            wf2[i] = (float)((v > t) - (v < -t));
        }
    }
}

// fc1 quantize, transposed to [k][f]; runs AFTER conv2
__global__ void k_quantF1(const float* __restrict__ w, const float* __restrict__ am,
                          float* __restrict__ wt) {
    float t = 0.05f * am[2];
    int i = blockIdx.x * 256 + threadIdx.x;        // 1048576 total
    float v = w[i];
    float q = (float)((v > t) - (v < -t));
    int f = i >> 11, k = i & 2047;
    wt[k * 512 + f] = q;
}

// conv1 pass A: stats only (no output write). Block per image, 512 threads.
// lane = output channel, wave index selects spatial stripe; window reads are
// wave-uniform LDS broadcasts; weights per-lane in 25 VGPRs.
__global__ __launch_bounds__(512) void k_conv1A(const float* __restrict__ x,
                                                const float* __restrict__ w1t,
                                                float* __restrict__ sum,
                                                float* __restrict__ ssq) {
    __shared__ float xs[784];
    __shared__ float red[2][8][64];
    int b = blockIdx.x;
    const float4* xim = (const float4*)(x + (size_t)b * 784);
    for (int i = threadIdx.x; i < 196; i += 512) ((float4*)xs)[i] = xim[i];
    int c  = threadIdx.x & 63;
    int wv = threadIdx.x >> 6;
    float w[25];
    #pragma unroll
    for (int k = 0; k < 25; ++k) w[k] = w1t[k * 64 + c];
    __syncthreads();
    float s = 0.f, s2 = 0.f;
    int oh = 0, ow = wv;                 // sp = it*8 + wv over [0,576)
    for (int it = 0; it < 72; ++it) {
        const float* xp = xs + oh * 28 + ow;
        float acc = 0.f;
        #pragma unroll
        for (int kh = 0; kh < 5; ++kh)
            #pragma unroll
            for (int kw = 0; kw < 5; ++kw)
                acc = fmaf(xp[kh * 28 + kw], w[kh * 5 + kw], acc);
        s += acc; s2 += acc * acc;
        ow += 8; if (ow >= 24) { ow -= 24; ++oh; }
    }
    red[0][wv][c] = s; red[1][wv][c] = s2;
    __syncthreads();
    if (threadIdx.x < 64) {
        float S = 0.f, S2 = 0.f;
        #pragma unroll
        for (int i = 0; i < 8; ++i) { S += red[0][i][threadIdx.x]; S2 += red[1][i][threadIdx.x]; }
        atomicAdd(&sum[threadIdx.x], S);
        atomicAdd(&ssq[threadIdx.x], S2);
    }
}

// conv1 pass B: recompute conv1 + bn + relu + 2x2 pool -> pool1 [512,64,12,12]
__global__ __launch_bounds__(512) void k_conv1B(const float* __restrict__ x,
                                                const float* __restrict__ w1t,
                                                const float* __restrict__ scale,
                                                const float* __restrict__ shift,
                                                float* __restrict__ pool1) {
    __shared__ float xs[784];
    int b = blockIdx.x;
    const float4* xim = (const float4*)(x + (size_t)b * 784);
    for (int i = threadIdx.x; i < 196; i += 512) ((float4*)xs)[i] = xim[i];
    int c  = threadIdx.x & 63;
    int wv = threadIdx.x >> 6;
    float w[25];
    #pragma unroll
    for (int k = 0; k < 25; ++k) w[k] = w1t[k * 64 + c];
    float sc = scale[c], sh = shift[c];
    __syncthreads();
    float* ob = pool1 + (size_t)b * 9216 + c * 144;
    int ph = 0, pw = wv;                 // psp = it*8 + wv over [0,144)
    for (int it = 0; it < 18; ++it) {
        const float* xp = xs + (ph * 2) * 28 + pw * 2;
        float win[36];
        #pragma unroll
        for (int i = 0; i < 6; ++i)
            #pragma unroll
            for (int j = 0; j < 6; ++j) win[i * 6 + j] = xp[i * 28 + j];
        float v00 = 0.f, v01 = 0.f, v10 = 0.f, v11 = 0.f;
        #pragma unroll
        for (int i = 0; i < 5; ++i)
            #pragma unroll
            for (int j = 0; j < 5; ++j) {
                float wk = w[i * 5 + j];
                v00 = fmaf(win[i * 6 + j],           wk, v00);
                v01 = fmaf(win[i * 6 + j + 1],       wk, v01);
                v10 = fmaf(win[(i + 1) * 6 + j],     wk, v10);
                v11 = fmaf(win[(i + 1) * 6 + j + 1], wk, v11);
            }
        float r0 = fmaxf(0.f, fmaf(v00, sc, sh));
        float r1 = fmaxf(0.f, fmaf(v01, sc, sh));
        float r2 = fmaxf(0.f, fmaf(v10, sc, sh));
        float r3 = fmaxf(0.f, fmaf(v11, sc, sh));
        ob[ph * 12 + pw] = fmaxf(fmaxf(r0, r1), fmaxf(r2, r3));
        pw += 8; if (pw >= 12) { pw -= 12; ++ph; }
    }
}

// conv2: pool1[512,64,12,12] -> out[512,128,8,8], fused bn2 stats.
// Grid 1024: (image, channel-half). Thread = (sp 64, 16-ch group per wave).
__global__ __launch_bounds__(256) void k_conv2(const float* __restrict__ xin,
                                               const float* __restrict__ w2,
                                               float* __restrict__ out,
                                               float* __restrict__ sum,
                                               float* __restrict__ ssq) {
    __shared__ float xs[9216];
    int b    = blockIdx.x >> 1;
    int half = blockIdx.x & 1;
    const float4* xim = (const float4*)(xin + (size_t)b * 9216);
    for (int i = threadIdx.x; i < 2304; i += 256) ((float4*)xs)[i] = xim[i];
    __syncthreads();
    int sp = threadIdx.x & 63;
    int oh = sp >> 3, ow = sp & 7;
    int c0 = __builtin_amdgcn_readfirstlane(half * 64 + (int)(threadIdx.x >> 6) * 16);
    float acc[16];
    #pragma unroll
    for (int c = 0; c < 16; ++c) acc[c] = 0.f;
    for (int ci = 0; ci < 64; ++ci) {
        float win[25];
        const float* xc = xs + ci * 144 + oh * 12 + ow;
        #pragma unroll
        for (int kh = 0; kh < 5; ++kh)
            #pragma unroll
            for (int kw = 0; kw < 5; ++kw)
                win[kh * 5 + kw] = xc[kh * 12 + kw];
        const float* wp = w2 + (ci * 128 + c0) * 25;
        #pragma unroll
        for (int c = 0; c < 16; ++c)
            #pragma unroll
            for (int k = 0; k < 25; ++k)
                acc[c] = fmaf(wp[c * 25 + k], win[k], acc[c]);
    }
    float* ob = out + ((size_t)b * 128 + c0) * 64 + sp;
    #pragma unroll
    for (int c = 0; c < 16; ++c) {
        float v = acc[c];
        ob[c * 64] = v;
        float s = v, s2 = v * v;
        #pragma unroll
        for (int o = 32; o; o >>= 1) { s += __shfl_down(s, o); s2 += __shfl_down(s2, o); }
        if (sp == 0) { atomicAdd(&sum[c0 + c], s); atomicAdd(&ssq[c0 + c], s2); }
    }
}

__global__ void k_finalize(const float* __restrict__ sum, const float* __restrict__ ssq,
                           const float* __restrict__ g, const float* __restrict__ bt,
                           float* __restrict__ scale, float* __restrict__ shift,
                           int C, float invN) {
    int c = blockIdx.x * blockDim.x + threadIdx.x;
    if (c >= C) return;
    float mean = sum[c] * invN;
    float var  = ssq[c] * invN - mean * mean;
    float sc   = g[c] * rsqrtf(var + EPS);
    scale[c] = sc;
    shift[c] = bt[c] - mean * sc;
}

// bn + relu + 2x2 maxpool (used for conv2 output only now)
__global__ void k_bnpool(const float* __restrict__ x, const float* __restrict__ scale,
                         const float* __restrict__ shift, float* __restrict__ out,
                         int C, int H, int W, int n) {
    int idx = blockIdx.x * blockDim.x + threadIdx.x;
    if (idx >= n) return;
    int Wo = W >> 1, Ho = H >> 1;
    int ow = idx % Wo; int t = idx / Wo;
    int oh = t % Ho;   t /= Ho;
    int c  = t % C;    int b = t / C;
    const float* xp = x + (((size_t)b * C + c) * H + oh * 2) * W + ow * 2;
    float sc = scale[c], sh = shift[c];
    float v0 = fmaxf(0.f, fmaf(xp[0],     sc, sh));
    float v1 = fmaxf(0.f, fmaf(xp[1],     sc, sh));
    float v2 = fmaxf(0.f, fmaf(xp[W],     sc, sh));
    float v3 = fmaxf(0.f, fmaf(xp[W + 1], sc, sh));
    out[idx] = fmaxf(fmaxf(v0, v1), fmaxf(v2, v3));
}

// fc1: pool2[512,2048] @ wt[2048,512] -> out[512,512]; 2 batches/thread
__global__ __launch_bounds__(256) void k_fc1(const float* __restrict__ x,
                                             const float* __restrict__ wt,
                                             float* __restrict__ out) {
    int idx = blockIdx.x * 256 + threadIdx.x;      // 131072
    int f = idx & 511;
    int bg = __builtin_amdgcn_readfirstlane(idx >> 9);  // 0..255, uniform/wave
    const float* x0 = x + (size_t)bg * 2 * 2048;
    float a0 = 0.f, a1 = 0.f;
    #pragma unroll 8
    for (int k = 0; k < 2048; ++k) {
        float wv = wt[k * 512 + f];
        a0 = fmaf(wv, x0[k],        a0);
        a1 = fmaf(wv, x0[2048 + k], a1);
    }
    float* o = out + (size_t)bg * 1024 + f;
    o[0] = a0; o[512] = a1;
}

__global__ void k_fcstats(const float* __restrict__ x, const float* __restrict__ g,
                          const float* __restrict__ bt,
                          float* __restrict__ scale, float* __restrict__ shift) {
    int f = blockIdx.x * blockDim.x + threadIdx.x;
    if (f >= 512) return;
    float s = 0.f, s2 = 0.f;
    for (int b = 0; b < 512; ++b) {
        float v = x[(size_t)b * 512 + f];
        s += v; s2 += v * v;
    }
    float mean = s * (1.f / 512.f);
    float var  = s2 * (1.f / 512.f) - mean * mean;
    float sc   = g[f] * rsqrtf(var + EPS);
    scale[f] = sc;
    shift[f] = bt[f] - mean * sc;
}

__global__ void k_fcbn(float* __restrict__ x, const float* __restrict__ scale,
                       const float* __restrict__ shift) {
    int i = blockIdx.x * 256 + threadIdx.x;        // 262144
    int f = i & 511;
    x[i] = fmaxf(0.f, fmaf(x[i], scale[f], shift[f]));
}

// fc2: x[512,512] @ w[10,512]^T + b -> out[512,10]
__global__ void k_fc2(const float* __restrict__ x, const float* __restrict__ w,
                      const float* __restrict__ bias, float* __restrict__ out) {
    int idx = blockIdx.x * blockDim.x + threadIdx.x;
    if (idx >= 5120) return;
    int j = idx % 10; int b = idx / 10;
    const float* xp = x + (size_t)b * 512;
    const float* wp = w + j * 512;
    float acc = bias[j];
    #pragma unroll 4
    for (int k = 0; k < 512; ++k) acc = fmaf(wp[k], xp[k], acc);
    out[idx] = acc;
}

extern "C" void kernel_launch(void* const* d_in, const int* in_sizes, int n_in,
                              void* d_out, int out_size, void* d_ws, size_t ws_size,
                              hipStream_t stream) {
    const float* x       = (const float*)d_in[0];
    const float* conv1_w = (const float*)d_in[1];
    const float* bn1_g   = (const float*)d_in[3];
    const float* bn1_b   = (const float*)d_in[4];
    const float* conv2_w = (const float*)d_in[5];
    const float* bn2_g   = (const float*)d_in[7];
    const float* bn2_b   = (const float*)d_in[8];
    const float* fc1_w   = (const float*)d_in[9];
    const float* bn3_g   = (const float*)d_in[11];
    const float* bn3_b   = (const float*)d_in[12];
    const float* fc2_w   = (const float*)d_in[13];
    const float* fc2_b   = (const float*)d_in[14];
    // conv1_b / conv2_b / fc1_b are absorbed by train-mode BN

    float* wsf = (float*)d_ws;

    float* c1_sum = wsf + 16,  * c1_ssq = wsf + 80;
    float* c1_sc  = wsf + 144, * c1_sh  = wsf + 208;
    float* c2_sum = wsf + 272, * c2_ssq = wsf + 400;
    float* c2_sc  = wsf + 528, * c2_sh  = wsf + 656;
    float* f_sc   = wsf + 784, * f_sh   = wsf + 1296;

    float* w1t = wsf + W1F;
    float* w2  = wsf + W2F;
    float* wf2 = wsf + WF2F;
    float* wt1 = wsf + WF1T;
    float* A   = wsf + A_F;
    float* Bb  = wsf + B_F;

    // stats/absmax zero
    k_zero<<<8, 256, 0, stream>>>(wsf, 2048);

    // absmax (all 4 tensors)
    k_absmax4<<<82, 256, 0, stream>>>(conv1_w, 1600, conv2_w, 204800,
                                      fc1_w, 1048576, fc2_w, 5120, wsf);

    // quantize conv1 (transposed [k][c]) / conv2 ([ci][c][25]) / fc2
    k_quantE<<<102, 256, 0, stream>>>(conv1_w, conv2_w, fc2_w, wsf, w1t, w2, wf2);

    // conv1 pass A: stats only
    k_conv1A<<<512, 512, 0, stream>>>(x, w1t, c1_sum, c1_ssq);
    k_finalize<<<1, 64, 0, stream>>>(c1_sum, c1_ssq, bn1_g, bn1_b, c1_sc, c1_sh, 64,
                                     1.f / 294912.f);

    // conv1 pass B: recompute + bn + relu + pool -> pool1 [512,64,12,12]
    k_conv1B<<<512, 512, 0, stream>>>(x, w1t, c1_sc, c1_sh, Bb);

    // conv2 (+ fused bn2 stats) -> A [512,128,8,8]
    k_conv2<<<1024, 256, 0, stream>>>(Bb, w2, A, c2_sum, c2_ssq);

    // fc1 weights (transposed), into dead pool1 region
    k_quantF1<<<4096, 256, 0, stream>>>(fc1_w, wsf, wt1);

    k_finalize<<<1, 128, 0, stream>>>(c2_sum, c2_ssq, bn2_g, bn2_b, c2_sc, c2_sh, 128,
                                      1.f / 32768.f);

    // bn+relu+pool -> B [512,128,4,4] (= [512,2048])
    k_bnpool<<<4096, 256, 0, stream>>>(A, c2_sc, c2_sh, Bb, 128, 8, 8, 1048576);

    // fc1 -> A [512,512]
    k_fc1<<<512, 256, 0, stream>>>(Bb, wt1, A);

    // bn3 stats + in-place bn+relu
    k_fcstats<<<2, 256, 0, stream>>>(A, bn3_g, bn3_b, f_sc, f_sh);
    k_fcbn<<<1024, 256, 0, stream>>>(A, f_sc, f_sh);

    // fc2 -> d_out [512,10]
    k_fc2<<<20, 256, 0, stream>>>(A, wf2, fc2_b, (float*)d_out);
}

// Round 4
// 380.545 us; speedup vs baseline: 4.7205x; 1.9571x over previous
//
#include <hip/hip_runtime.h>
#include <stdint.h>

#define EPS 1e-5f

typedef short v8s __attribute__((ext_vector_type(8)));
typedef float v4f __attribute__((ext_vector_type(4)));

// ---------------- ws float layout ----------------
//  [0,4)     absmax {c1,c2,f1,f2}
//  16/80/144/208    c1 sum/ssq/scale/shift (64 each)
//  272/400/528/656  c2 sum/ssq/scale/shift (128 each)
//  784 fc scale(512) 1296 fc shift(512)
//  W1F  = 2048    : conv1 weights float [k=25][c=64]        (1600 f)
//  W2F  = 4096    : conv2 weights bf16 MFMA-frag order      (204800 ushort = 102400 f)
//  WF2F = 212992  : fc2 weights float [j][512]              (5120 f)
//  A_F  = 262144  : A: conv2out fp32 [512,128,8,8] / fc1out [512,512]
//  B_F  = 19136512: B: pool1 bf16 NHWC [512][144][64] (2359296 f-slots)
//                      then pool2 fp32 [512,2048] (first 1048576 f)
//  WF1T = B_F + 1048576 : fc1 weights float [k=2048][f=512] (1048576 f)
//         (overlaps pool1's tail; written AFTER conv2 when pool1 is dead)
static const size_t W1F  = 2048;
static const size_t W2F  = 4096;
static const size_t WF2F = 212992;
static const size_t A_F  = 262144;
static const size_t B_F  = 19136512;
static const size_t WF1T = B_F + 1048576;

__device__ inline unsigned short f2bf(float f) {
    unsigned u = __float_as_uint(f);
    return (unsigned short)((u + 0x7FFF + ((u >> 16) & 1)) >> 16);
}

__global__ void k_zero(float* p, int n) {
    int i = blockIdx.x * blockDim.x + threadIdx.x;
    if (i < n) p[i] = 0.f;
}

// 4 absmax reductions in one launch
__global__ void k_absmax4(const float* __restrict__ w0, int n0,
                          const float* __restrict__ w1, int n1,
                          const float* __restrict__ w2, int n2,
                          const float* __restrict__ w3, int n3,
                          float* outv) {
    int blk = blockIdx.x;
    const float* w; int n; unsigned* out; int nb; int bi;
    if (blk < 1)       { w = w0; n = n0; out = (unsigned*)(outv + 0); nb = 1;  bi = blk;      }
    else if (blk < 17) { w = w1; n = n1; out = (unsigned*)(outv + 1); nb = 16; bi = blk - 1;  }
    else if (blk < 81) { w = w2; n = n2; out = (unsigned*)(outv + 2); nb = 64; bi = blk - 17; }
    else               { w = w3; n = n3; out = (unsigned*)(outv + 3); nb = 1;  bi = blk - 81; }
    float m = 0.f;
    for (int i = bi * 256 + threadIdx.x; i < n; i += nb * 256)
        m = fmaxf(m, fabsf(w[i]));
    #pragma unroll
    for (int o = 32; o; o >>= 1) m = fmaxf(m, __shfl_down(m, o));
    if ((threadIdx.x & 63) == 0) atomicMax(out, __float_as_uint(m));
}

// quantize: conv1 -> w1t float [k=25][c=64]; conv2 -> bf16 MFMA-fragment order;
// fc2 -> float straight
// conv2 frag layout: idx = ((p*2+ks)*8 + mt)*512 + lane*8 + j
//   element = Q(conv2_w[c][ci][p]), c = mt*16 + (lane&15), ci = ks*32 + (lane>>4)*8 + j
__global__ void k_quantE(const float* __restrict__ c1w, const float* __restrict__ c2w,
                         const float* __restrict__ f2w, const float* __restrict__ am,
                         float* __restrict__ w1t, unsigned short* __restrict__ w2u,
                         float* __restrict__ wf2) {
    int blk = blockIdx.x;
    if (blk < 1) {                       // conv1: 1600, transpose to [k][c]
        float t = 0.05f * am[0];
        for (int i = threadIdx.x; i < 1600; i += 256) {
            float v = c1w[i];
            float q = (float)((v > t) - (v < -t));
            int c = i / 25, k = i - c * 25;
            w1t[k * 64 + c] = q;
        }
    } else if (blk < 101) {              // conv2: 204800 = 100 * 2048
        float t = 0.05f * am[1];
        int base = (blk - 1) * 2048;
        #pragma unroll
        for (int jj = 0; jj < 8; ++jj) {
            int i = base + jj * 256 + threadIdx.x;
            int j    = i & 7;
            int lane = (i >> 3) & 63;
            int mt   = (i >> 9) & 7;
            int ks   = (i >> 12) & 1;
            int p    = i >> 13;
            int c  = mt * 16 + (lane & 15);
            int ci = ks * 32 + (lane >> 4) * 8 + j;
            float v = c2w[c * 1600 + ci * 25 + p];
            w2u[i] = (v > t) ? (unsigned short)0x3F80
                             : ((v < -t) ? (unsigned short)0xBF80 : (unsigned short)0);
        }
    } else {                             // fc2: 5120
        float t = 0.05f * am[3];
        for (int i = threadIdx.x; i < 5120; i += 256) {
            float v = f2w[i];
            wf2[i] = (float)((v > t) - (v < -t));
        }
    }
}

// fc1 quantize, transposed to [k][f]; runs AFTER conv2 (overlaps dead pool1)
__global__ void k_quantF1(const float* __restrict__ w, const float* __restrict__ am,
                          float* __restrict__ wt) {
    float t = 0.05f * am[2];
    int i = blockIdx.x * 256 + threadIdx.x;        // 1048576 total
    float v = w[i];
    float q = (float)((v > t) - (v < -t));
    int f = i >> 11, k = i & 2047;
    wt[k * 512 + f] = q;
}

// conv1 pass A: stats only. Block per image, 512 threads; lane = out channel.
__global__ __launch_bounds__(512) void k_conv1A(const float* __restrict__ x,
                                                const float* __restrict__ w1t,
                                                float* __restrict__ sum,
                                                float* __restrict__ ssq) {
    __shared__ float xs[784];
    __shared__ float red[2][8][64];
    int b = blockIdx.x;
    const float4* xim = (const float4*)(x + (size_t)b * 784);
    for (int i = threadIdx.x; i < 196; i += 512) ((float4*)xs)[i] = xim[i];
    int c  = threadIdx.x & 63;
    int wv = threadIdx.x >> 6;
    float w[25];
    #pragma unroll
    for (int k = 0; k < 25; ++k) w[k] = w1t[k * 64 + c];
    __syncthreads();
    float s = 0.f, s2 = 0.f;
    int oh = 0, ow = wv;
    for (int it = 0; it < 72; ++it) {
        const float* xp = xs + oh * 28 + ow;
        float acc = 0.f;
        #pragma unroll
        for (int kh = 0; kh < 5; ++kh)
            #pragma unroll
            for (int kw = 0; kw < 5; ++kw)
                acc = fmaf(xp[kh * 28 + kw], w[kh * 5 + kw], acc);
        s += acc; s2 += acc * acc;
        ow += 8; if (ow >= 24) { ow -= 24; ++oh; }
    }
    red[0][wv][c] = s; red[1][wv][c] = s2;
    __syncthreads();
    if (threadIdx.x < 64) {
        float S = 0.f, S2 = 0.f;
        #pragma unroll
        for (int i = 0; i < 8; ++i) { S += red[0][i][threadIdx.x]; S2 += red[1][i][threadIdx.x]; }
        atomicAdd(&sum[threadIdx.x], S);
        atomicAdd(&ssq[threadIdx.x], S2);
    }
}

// conv1 pass B: recompute conv1 + bn + relu + pool -> pool1 NHWC bf16 [b][144][64]
__global__ __launch_bounds__(512) void k_conv1B(const float* __restrict__ x,
                                                const float* __restrict__ w1t,
                                                const float* __restrict__ scale,
                                                const float* __restrict__ shift,
                                                unsigned short* __restrict__ pool1) {
    __shared__ float xs[784];
    int b = blockIdx.x;
    const float4* xim = (const float4*)(x + (size_t)b * 784);
    for (int i = threadIdx.x; i < 196; i += 512) ((float4*)xs)[i] = xim[i];
    int c  = threadIdx.x & 63;
    int wv = threadIdx.x >> 6;
    float w[25];
    #pragma unroll
    for (int k = 0; k < 25; ++k) w[k] = w1t[k * 64 + c];
    float sc = scale[c], sh = shift[c];
    __syncthreads();
    unsigned short* ob = pool1 + (size_t)b * 9216;
    int ph = 0, pw = wv;
    for (int it = 0; it < 18; ++it) {
        const float* xp = xs + (ph * 2) * 28 + pw * 2;
        float win[36];
        #pragma unroll
        for (int i = 0; i < 6; ++i)
            #pragma unroll
            for (int j = 0; j < 6; ++j) win[i * 6 + j] = xp[i * 28 + j];
        float v00 = 0.f, v01 = 0.f, v10 = 0.f, v11 = 0.f;
        #pragma unroll
        for (int i = 0; i < 5; ++i)
            #pragma unroll
            for (int j = 0; j < 5; ++j) {
                float wk = w[i * 5 + j];
                v00 = fmaf(win[i * 6 + j],           wk, v00);
                v01 = fmaf(win[i * 6 + j + 1],       wk, v01);
                v10 = fmaf(win[(i + 1) * 6 + j],     wk, v10);
                v11 = fmaf(win[(i + 1) * 6 + j + 1], wk, v11);
            }
        float r0 = fmaxf(0.f, fmaf(v00, sc, sh));
        float r1 = fmaxf(0.f, fmaf(v01, sc, sh));
        float r2 = fmaxf(0.f, fmaf(v10, sc, sh));
        float r3 = fmaxf(0.f, fmaf(v11, sc, sh));
        ob[(ph * 12 + pw) * 64 + c] = f2bf(fmaxf(fmaxf(r0, r1), fmaxf(r2, r3)));
        pw += 8; if (pw >= 12) { pw -= 12; ++ph; }
    }
}

// conv2 MFMA: pool1 NHWC bf16 -> A fp32 [512,128,8,8] via atomicAdd (A pre-zeroed).
// Grid 1024 = (image, pos-half). 4 waves; wave = 16-sp quarter; per wave M=128.
__global__ __launch_bounds__(256) void k_conv2(const unsigned short* __restrict__ pool1,
                                               const unsigned short* __restrict__ wfrag,
                                               float* __restrict__ out) {
    __shared__ unsigned short xs[144 * 72];        // ldci=72 pad (20736 B)
    int b  = blockIdx.x >> 1;
    int ph = blockIdx.x & 1;
    const unsigned short* src = pool1 + (size_t)b * 9216;
    for (int i = threadIdx.x; i < 1152; i += 256) {
        int r = i >> 3, part = i & 7;
        *(float4*)(&xs[r * 72 + part * 8]) = *(const float4*)(src + r * 64 + part * 8);
    }
    __syncthreads();
    int lane = threadIdx.x & 63;
    int wave = threadIdx.x >> 6;
    int n = lane & 15, quad = lane >> 4;
    int sp = wave * 16 + n;
    int bbase = ((sp >> 3) * 12 + (sp & 7)) * 72 + quad * 8;
    v4f acc[8];
    #pragma unroll
    for (int mt = 0; mt < 8; ++mt) acc[mt] = (v4f){0.f, 0.f, 0.f, 0.f};
    int p0 = ph ? 13 : 0, p1 = ph ? 25 : 13;
    for (int p = p0; p < p1; ++p) {
        int kh = p / 5, kw = p - kh * 5;
        int boff = bbase + (kh * 12 + kw) * 72;
        #pragma unroll
        for (int ks = 0; ks < 2; ++ks) {
            v8s bfrag = *(const v8s*)(&xs[boff + ks * 32]);
            const unsigned short* wp = wfrag + (size_t)((p * 2 + ks) * 8) * 512 + lane * 8;
            #pragma unroll
            for (int mt = 0; mt < 8; ++mt) {
                v8s afrag = *(const v8s*)(wp + mt * 512);
                acc[mt] = __builtin_amdgcn_mfma_f32_16x16x32_bf16(afrag, bfrag, acc[mt], 0, 0, 0);
            }
        }
    }
    float* ob = out + (size_t)b * 128 * 64;
    #pragma unroll
    for (int mt = 0; mt < 8; ++mt) {
        int c0 = mt * 16 + quad * 4;
        #pragma unroll
        for (int r = 0; r < 4; ++r)
            atomicAdd(&ob[(c0 + r) * 64 + sp], acc[mt][r]);
    }
}

// per-channel sum/sumsq over [B,C,HW]
__global__ void k_stats(const float* __restrict__ x, int C, int HW, int B,
                        float* __restrict__ sum, float* __restrict__ ssq) {
    int c = blockIdx.x;
    int total = B * HW;
    float s = 0.f, s2 = 0.f;
    for (int i = blockIdx.y * blockDim.x + threadIdx.x; i < total; i += gridDim.y * blockDim.x) {
        int b = i / HW; int hw = i - b * HW;
        float v = x[((size_t)b * C + c) * HW + hw];
        s += v; s2 += v * v;
    }
    #pragma unroll
    for (int o = 32; o; o >>= 1) { s += __shfl_down(s, o); s2 += __shfl_down(s2, o); }
    if ((threadIdx.x & 63) == 0) { atomicAdd(&sum[c], s); atomicAdd(&ssq[c], s2); }
}

__global__ void k_finalize(const float* __restrict__ sum, const float* __restrict__ ssq,
                           const float* __restrict__ g, const float* __restrict__ bt,
                           float* __restrict__ scale, float* __restrict__ shift,
                           int C, float invN) {
    int c = blockIdx.x * blockDim.x + threadIdx.x;
    if (c >= C) return;
    float mean = sum[c] * invN;
    float var  = ssq[c] * invN - mean * mean;
    float sc   = g[c] * rsqrtf(var + EPS);
    scale[c] = sc;
    shift[c] = bt[c] - mean * sc;
}

// bn + relu + 2x2 maxpool (conv2 output -> pool2 fp32)
__global__ void k_bnpool(const float* __restrict__ x, const float* __restrict__ scale,
                         const float* __restrict__ shift, float* __restrict__ out,
                         int C, int H, int W, int n) {
    int idx = blockIdx.x * blockDim.x + threadIdx.x;
    if (idx >= n) return;
    int Wo = W >> 1, Ho = H >> 1;
    int ow = idx % Wo; int t = idx / Wo;
    int oh = t % Ho;   t /= Ho;
    int c  = t % C;    int b = t / C;
    const float* xp = x + (((size_t)b * C + c) * H + oh * 2) * W + ow * 2;
    float sc = scale[c], sh = shift[c];
    float v0 = fmaxf(0.f, fmaf(xp[0],     sc, sh));
    float v1 = fmaxf(0.f, fmaf(xp[1],     sc, sh));
    float v2 = fmaxf(0.f, fmaf(xp[W],     sc, sh));
    float v3 = fmaxf(0.f, fmaf(xp[W + 1], sc, sh));
    out[idx] = fmaxf(fmaxf(v0, v1), fmaxf(v2, v3));
}

// fc1: pool2[512,2048] @ wt[2048,512] -> out[512,512]; 2 batches/thread
__global__ __launch_bounds__(256) void k_fc1(const float* __restrict__ x,
                                             const float* __restrict__ wt,
                                             float* __restrict__ out) {
    int idx = blockIdx.x * 256 + threadIdx.x;      // 131072
    int f = idx & 511;
    int bg = __builtin_amdgcn_readfirstlane(idx >> 9);
    const float* x0 = x + (size_t)bg * 2 * 2048;
    float a0 = 0.f, a1 = 0.f;
    #pragma unroll 8
    for (int k = 0; k < 2048; ++k) {
        float wv = wt[k * 512 + f];
        a0 = fmaf(wv, x0[k],        a0);
        a1 = fmaf(wv, x0[2048 + k], a1);
    }
    float* o = out + (size_t)bg * 1024 + f;
    o[0] = a0; o[512] = a1;
}

__global__ void k_fcstats(const float* __restrict__ x, const float* __restrict__ g,
                          const float* __restrict__ bt,
                          float* __restrict__ scale, float* __restrict__ shift) {
    int f = blockIdx.x * blockDim.x + threadIdx.x;
    if (f >= 512) return;
    float s = 0.f, s2 = 0.f;
    for (int b = 0; b < 512; ++b) {
        float v = x[(size_t)b * 512 + f];
        s += v; s2 += v * v;
    }
    float mean = s * (1.f / 512.f);
    float var  = s2 * (1.f / 512.f) - mean * mean;
    float sc   = g[f] * rsqrtf(var + EPS);
    scale[f] = sc;
    shift[f] = bt[f] - mean * sc;
}

__global__ void k_fcbn(float* __restrict__ x, const float* __restrict__ scale,
                       const float* __restrict__ shift) {
    int i = blockIdx.x * 256 + threadIdx.x;        // 262144
    int f = i & 511;
    x[i] = fmaxf(0.f, fmaf(x[i], scale[f], shift[f]));
}

// fc2: x[512,512] @ w[10,512]^T + b -> out[512,10]
__global__ void k_fc2(const float* __restrict__ x, const float* __restrict__ w,
                      const float* __restrict__ bias, float* __restrict__ out) {
    int idx = blockIdx.x * blockDim.x + threadIdx.x;
    if (idx >= 5120) return;
    int j = idx % 10; int b = idx / 10;
    const float* xp = x + (size_t)b * 512;
    const float* wp = w + j * 512;
    float acc = bias[j];
    #pragma unroll 4
    for (int k = 0; k < 512; ++k) acc = fmaf(wp[k], xp[k], acc);
    out[idx] = acc;
}

extern "C" void kernel_launch(void* const* d_in, const int* in_sizes, int n_in,
                              void* d_out, int out_size, void* d_ws, size_t ws_size,
                              hipStream_t stream) {
    const float* x       = (const float*)d_in[0];
    const float* conv1_w = (const float*)d_in[1];
    const float* bn1_g   = (const float*)d_in[3];
    const float* bn1_b   = (const float*)d_in[4];
    const float* conv2_w = (const float*)d_in[5];
    const float* bn2_g   = (const float*)d_in[7];
    const float* bn2_b   = (const float*)d_in[8];
    const float* fc1_w   = (const float*)d_in[9];
    const float* bn3_g   = (const float*)d_in[11];
    const float* bn3_b   = (const float*)d_in[12];
    const float* fc2_w   = (const float*)d_in[13];
    const float* fc2_b   = (const float*)d_in[14];
    // conv1_b / conv2_b / fc1_b are absorbed by train-mode BN

    float* wsf = (float*)d_ws;

    float* c1_sum = wsf + 16,  * c1_ssq = wsf + 80;
    float* c1_sc  = wsf + 144, * c1_sh  = wsf + 208;
    float* c2_sum = wsf + 272, * c2_ssq = wsf + 400;
    float* c2_sc  = wsf + 528, * c2_sh  = wsf + 656;
    float* f_sc   = wsf + 784, * f_sh   = wsf + 1296;

    float* w1t = wsf + W1F;
    unsigned short* w2u = (unsigned short*)(wsf + W2F);
    float* wf2 = wsf + WF2F;
    float* wt1 = wsf + WF1T;
    float* A   = wsf + A_F;
    unsigned short* pool1 = (unsigned short*)(wsf + B_F);
    float* pool2 = wsf + B_F;

    // zero stats + conv2 accumulator
    k_zero<<<8, 256, 0, stream>>>(wsf, 2048);
    k_zero<<<16384, 256, 0, stream>>>(A, 4194304);

    // absmax (all 4 tensors)
    k_absmax4<<<82, 256, 0, stream>>>(conv1_w, 1600, conv2_w, 204800,
                                      fc1_w, 1048576, fc2_w, 5120, wsf);

    // quantize conv1 / conv2 (MFMA-frag bf16) / fc2
    k_quantE<<<102, 256, 0, stream>>>(conv1_w, conv2_w, fc2_w, wsf, w1t, w2u, wf2);

    // conv1 pass A: stats only
    k_conv1A<<<512, 512, 0, stream>>>(x, w1t, c1_sum, c1_ssq);
    k_finalize<<<1, 64, 0, stream>>>(c1_sum, c1_ssq, bn1_g, bn1_b, c1_sc, c1_sh, 64,
                                     1.f / 294912.f);

    // conv1 pass B: recompute + bn + relu + pool -> pool1 NHWC bf16
    k_conv1B<<<512, 512, 0, stream>>>(x, w1t, c1_sc, c1_sh, pool1);

    // conv2 MFMA -> A (atomic accumulate over 2 pos-halves)
    k_conv2<<<1024, 256, 0, stream>>>(pool1, w2u, A);

    // fc1 weights (transposed), into dead pool1 region
    k_quantF1<<<4096, 256, 0, stream>>>(fc1_w, wsf, wt1);

    // bn2 stats + finalize
    { dim3 g(128, 8); k_stats<<<g, 256, 0, stream>>>(A, 128, 64, 512, c2_sum, c2_ssq); }
    k_finalize<<<1, 128, 0, stream>>>(c2_sum, c2_ssq, bn2_g, bn2_b, c2_sc, c2_sh, 128,
                                      1.f / 32768.f);

    // bn+relu+pool -> pool2 fp32 [512,2048]
    k_bnpool<<<4096, 256, 0, stream>>>(A, c2_sc, c2_sh, pool2, 128, 8, 8, 1048576);

    // fc1 -> A [512,512]
    k_fc1<<<512, 256, 0, stream>>>(pool2, wt1, A);

    // bn3 stats + in-place bn+relu
    k_fcstats<<<2, 256, 0, stream>>>(A, bn3_g, bn3_b, f_sc, f_sh);
    k_fcbn<<<1024, 256, 0, stream>>>(A, f_sc, f_sh);

    // fc2 -> d_out [512,10]
    k_fc2<<<20, 256, 0, stream>>>(A, wf2, fc2_b, (float*)d_out);
}

// Round 6
// 278.344 us; speedup vs baseline: 6.4538x; 1.3672x over previous
//
#include <hip/hip_runtime.h>
#include <stdint.h>

#define EPS 1e-5f

typedef short v8s __attribute__((ext_vector_type(8)));
typedef float v4f __attribute__((ext_vector_type(4)));

// ---------------- ws float layout ----------------
//  [0,4)     absmax {c1,c2,f1,f2}
//  16/80/144/208    c1 sum/ssq/scale/shift (64 each)
//  272/400/528/656  c2 sum/ssq/scale/shift (128 each)
//  784 fc scale(512) 1296 fc shift(512)  1808 fc sum(512) 2320 fc ssq(512)
//  W1F  = 4096    : conv1 weights float [k=25][c=64]        (1600 f)
//  W2F  = 8192    : conv2 weights bf16 MFMA-frag order      (204800 us = 102400 f)
//  WF2F = 212992  : fc2 weights float [j][512]              (5120 f)
//  A_F  = 262144  : A: conv2out fp32 [512,128,8,8] / fc1out fp32 [512,512]
//  B_F  = 19136512: pool1 bf16 NHWC [512][144][64] (4718592 us = 2359296 f-slots)
//                   then pool2 bf16 B-frag (1048576 us = 524288 f-slots)
//  WF1T = B_F + 1048576 : fc1 weights bf16 A-frag (1048576 us = 524288 f-slots)
//         overlaps pool1 tail; written AFTER conv2 when pool1 is dead
static const size_t W1F  = 4096;
static const size_t W2F  = 8192;
static const size_t WF2F = 212992;
static const size_t A_F  = 262144;
static const size_t B_F  = 19136512;
static const size_t WF1T = B_F + 1048576;

__device__ inline unsigned short f2bf(float f) {
    unsigned u = __float_as_uint(f);
    return (unsigned short)((u + 0x7FFF + ((u >> 16) & 1)) >> 16);
}

__global__ void k_zero(float* p, int n) {
    int i = blockIdx.x * blockDim.x + threadIdx.x;
    if (i < n) p[i] = 0.f;
}

// 4 absmax reductions in one launch
__global__ void k_absmax4(const float* __restrict__ w0, int n0,
                          const float* __restrict__ w1, int n1,
                          const float* __restrict__ w2, int n2,
                          const float* __restrict__ w3, int n3,
                          float* outv) {
    int blk = blockIdx.x;
    const float* w; int n; unsigned* out; int nb; int bi;
    if (blk < 1)       { w = w0; n = n0; out = (unsigned*)(outv + 0); nb = 1;  bi = blk;      }
    else if (blk < 17) { w = w1; n = n1; out = (unsigned*)(outv + 1); nb = 16; bi = blk - 1;  }
    else if (blk < 81) { w = w2; n = n2; out = (unsigned*)(outv + 2); nb = 64; bi = blk - 17; }
    else               { w = w3; n = n3; out = (unsigned*)(outv + 3); nb = 1;  bi = blk - 81; }
    float m = 0.f;
    for (int i = bi * 256 + threadIdx.x; i < n; i += nb * 256)
        m = fmaxf(m, fabsf(w[i]));
    #pragma unroll
    for (int o = 32; o; o >>= 1) m = fmaxf(m, __shfl_down(m, o));
    if ((threadIdx.x & 63) == 0) atomicMax(out, __float_as_uint(m));
}

// quantize: conv1 -> w1t float [k=25][c=64]; conv2 -> bf16 A-frag order; fc2 float
// conv2 frag: idx = ((p*2+ks)*8 + mt)*512 + lane*8 + j
//   = Q(conv2_w[c][ci][p]), c = mt*16 + (lane&15), ci = ks*32 + (lane>>4)*8 + j
__global__ void k_quantE(const float* __restrict__ c1w, const float* __restrict__ c2w,
                         const float* __restrict__ f2w, const float* __restrict__ am,
                         float* __restrict__ w1t, unsigned short* __restrict__ w2u,
                         float* __restrict__ wf2) {
    int blk = blockIdx.x;
    if (blk < 1) {
        float t = 0.05f * am[0];
        for (int i = threadIdx.x; i < 1600; i += 256) {
            float v = c1w[i];
            float q = (float)((v > t) - (v < -t));
            int c = i / 25, k = i - c * 25;
            w1t[k * 64 + c] = q;
        }
    } else if (blk < 101) {
        float t = 0.05f * am[1];
        int base = (blk - 1) * 2048;
        #pragma unroll
        for (int jj = 0; jj < 8; ++jj) {
            int i = base + jj * 256 + threadIdx.x;
            int j    = i & 7;
            int lane = (i >> 3) & 63;
            int mt   = (i >> 9) & 7;
            int ks   = (i >> 12) & 1;
            int p    = i >> 13;
            int c  = mt * 16 + (lane & 15);
            int ci = ks * 32 + (lane >> 4) * 8 + j;
            float v = c2w[c * 1600 + ci * 25 + p];
            w2u[i] = (v > t) ? (unsigned short)0x3F80
                             : ((v < -t) ? (unsigned short)0xBF80 : (unsigned short)0);
        }
    } else {
        float t = 0.05f * am[3];
        for (int i = threadIdx.x; i < 5120; i += 256) {
            float v = f2w[i];
            wf2[i] = (float)((v > t) - (v < -t));
        }
    }
}

// fc1 quantize -> bf16 A-frag: idx = ((ks*32 + ft)*64 + lane)*8 + j
//   = Q(fc1_w[f][k]), f = ft*16 + (lane&15), k = ks*32 + (lane>>4)*8 + j
// 1048576 elements total -> grid 4096 x 256 (NOT 8192: ks = i>>14 must stay < 64)
__global__ void k_quantF1(const float* __restrict__ w, const float* __restrict__ am,
                          unsigned short* __restrict__ wf) {
    float t = 0.05f * am[2];
    int i = blockIdx.x * 256 + threadIdx.x;        // 1048576 total
    int j    = i & 7;
    int lane = (i >> 3) & 63;
    int ft   = (i >> 9) & 31;
    int ks   = i >> 14;                            // [0,64)
    int f = ft * 16 + (lane & 15);
    int k = ks * 32 + (lane >> 4) * 8 + j;
    float v = w[f * 2048 + k];
    wf[i] = (v > t) ? (unsigned short)0x3F80
                    : ((v < -t) ? (unsigned short)0xBF80 : (unsigned short)0);
}

// conv1 pass A: stats only. Block per image, 512 threads; lane = out channel.
__global__ __launch_bounds__(512) void k_conv1A(const float* __restrict__ x,
                                                const float* __restrict__ w1t,
                                                float* __restrict__ sum,
                                                float* __restrict__ ssq) {
    __shared__ float xs[784];
    __shared__ float red[2][8][64];
    int b = blockIdx.x;
    const float4* xim = (const float4*)(x + (size_t)b * 784);
    for (int i = threadIdx.x; i < 196; i += 512) ((float4*)xs)[i] = xim[i];
    int c  = threadIdx.x & 63;
    int wv = threadIdx.x >> 6;
    float w[25];
    #pragma unroll
    for (int k = 0; k < 25; ++k) w[k] = w1t[k * 64 + c];
    __syncthreads();
    float s = 0.f, s2 = 0.f;
    int oh = 0, ow = wv;
    for (int it = 0; it < 72; ++it) {
        const float* xp = xs + oh * 28 + ow;
        float acc = 0.f;
        #pragma unroll
        for (int kh = 0; kh < 5; ++kh)
            #pragma unroll
            for (int kw = 0; kw < 5; ++kw)
                acc = fmaf(xp[kh * 28 + kw], w[kh * 5 + kw], acc);
        s += acc; s2 += acc * acc;
        ow += 8; if (ow >= 24) { ow -= 24; ++oh; }
    }
    red[0][wv][c] = s; red[1][wv][c] = s2;
    __syncthreads();
    if (threadIdx.x < 64) {
        float S = 0.f, S2 = 0.f;
        #pragma unroll
        for (int i = 0; i < 8; ++i) { S += red[0][i][threadIdx.x]; S2 += red[1][i][threadIdx.x]; }
        atomicAdd(&sum[threadIdx.x], S);
        atomicAdd(&ssq[threadIdx.x], S2);
    }
}

// conv1 pass B: recompute conv1 + bn + relu + pool -> pool1 NHWC bf16 [b][144][64]
__global__ __launch_bounds__(512) void k_conv1B(const float* __restrict__ x,
                                                const float* __restrict__ w1t,
                                                const float* __restrict__ scale,
                                                const float* __restrict__ shift,
                                                unsigned short* __restrict__ pool1) {
    __shared__ float xs[784];
    int b = blockIdx.x;
    const float4* xim = (const float4*)(x + (size_t)b * 784);
    for (int i = threadIdx.x; i < 196; i += 512) ((float4*)xs)[i] = xim[i];
    int c  = threadIdx.x & 63;
    int wv = threadIdx.x >> 6;
    float w[25];
    #pragma unroll
    for (int k = 0; k < 25; ++k) w[k] = w1t[k * 64 + c];
    float sc = scale[c], sh = shift[c];
    __syncthreads();
    unsigned short* ob = pool1 + (size_t)b * 9216;
    int ph = 0, pw = wv;
    for (int it = 0; it < 18; ++it) {
        const float* xp = xs + (ph * 2) * 28 + pw * 2;
        float win[36];
        #pragma unroll
        for (int i = 0; i < 6; ++i)
            #pragma unroll
            for (int j = 0; j < 6; ++j) win[i * 6 + j] = xp[i * 28 + j];
        float v00 = 0.f, v01 = 0.f, v10 = 0.f, v11 = 0.f;
        #pragma unroll
        for (int i = 0; i < 5; ++i)
            #pragma unroll
            for (int j = 0; j < 5; ++j) {
                float wk = w[i * 5 + j];
                v00 = fmaf(win[i * 6 + j],           wk, v00);
                v01 = fmaf(win[i * 6 + j + 1],       wk, v01);
                v10 = fmaf(win[(i + 1) * 6 + j],     wk, v10);
                v11 = fmaf(win[(i + 1) * 6 + j + 1], wk, v11);
            }
        float r0 = fmaxf(0.f, fmaf(v00, sc, sh));
        float r1 = fmaxf(0.f, fmaf(v01, sc, sh));
        float r2 = fmaxf(0.f, fmaf(v10, sc, sh));
        float r3 = fmaxf(0.f, fmaf(v11, sc, sh));
        ob[(ph * 12 + pw) * 64 + c] = f2bf(fmaxf(fmaxf(r0, r1), fmaxf(r2, r3)));
        pw += 8; if (pw >= 12) { pw -= 12; ++ph; }
    }
}

// conv2 MFMA v2: full K per block (no atomics on out), fused bn2 stats.
// Block per image; 4 waves x 16 sp; M=128 via 8 mt tiles.
__global__ __launch_bounds__(256) void k_conv2(const unsigned short* __restrict__ pool1,
                                               const unsigned short* __restrict__ wfrag,
                                               float* __restrict__ out,
                                               float* __restrict__ sum,
                                               float* __restrict__ ssq) {
    __shared__ unsigned short xs[144 * 72];        // 20736 B
    __shared__ float reds[4][128], redq[4][128];
    int b = blockIdx.x;
    const unsigned short* src = pool1 + (size_t)b * 9216;
    for (int i = threadIdx.x; i < 1152; i += 256) {
        int r = i >> 3, part = i & 7;
        *(float4*)(&xs[r * 72 + part * 8]) = *(const float4*)(src + r * 64 + part * 8);
    }
    __syncthreads();
    int lane = threadIdx.x & 63;
    int wave = threadIdx.x >> 6;
    int n = lane & 15, quad = lane >> 4;
    int sp = wave * 16 + n;
    int bbase = ((sp >> 3) * 12 + (sp & 7)) * 72 + quad * 8;
    v4f acc[8];
    #pragma unroll
    for (int mt = 0; mt < 8; ++mt) acc[mt] = (v4f){0.f, 0.f, 0.f, 0.f};
    for (int p = 0; p < 25; ++p) {
        int kh = p / 5, kw = p - kh * 5;
        int boff = bbase + (kh * 12 + kw) * 72;
        #pragma unroll
        for (int ks = 0; ks < 2; ++ks) {
            v8s bfrag = *(const v8s*)(&xs[boff + ks * 32]);
            const unsigned short* wp = wfrag + (size_t)((p * 2 + ks) * 8) * 512 + lane * 8;
            #pragma unroll
            for (int mt = 0; mt < 8; ++mt) {
                v8s afrag = *(const v8s*)(wp + mt * 512);
                acc[mt] = __builtin_amdgcn_mfma_f32_16x16x32_bf16(afrag, bfrag, acc[mt], 0, 0, 0);
            }
        }
    }
    float* ob = out + (size_t)b * 8192;
    #pragma unroll
    for (int mt = 0; mt < 8; ++mt) {
        int c0 = mt * 16 + quad * 4;
        #pragma unroll
        for (int r = 0; r < 4; ++r) {
            float v = acc[mt][r];
            ob[(c0 + r) * 64 + sp] = v;
            float s = v, s2 = v * v;
            #pragma unroll
            for (int m = 1; m < 16; m <<= 1) { s += __shfl_xor(s, m); s2 += __shfl_xor(s2, m); }
            if (n == 0) { reds[wave][c0 + r] = s; redq[wave][c0 + r] = s2; }
        }
    }
    __syncthreads();
    if (threadIdx.x < 128) {
        int c = threadIdx.x;
        float S  = reds[0][c] + reds[1][c] + reds[2][c] + reds[3][c];
        float S2 = redq[0][c] + redq[1][c] + redq[2][c] + redq[3][c];
        atomicAdd(&sum[c], S);
        atomicAdd(&ssq[c], S2);
    }
}

__global__ void k_finalize(const float* __restrict__ sum, const float* __restrict__ ssq,
                           const float* __restrict__ g, const float* __restrict__ bt,
                           float* __restrict__ scale, float* __restrict__ shift,
                           int C, float invN) {
    int c = blockIdx.x * blockDim.x + threadIdx.x;
    if (c >= C) return;
    float mean = sum[c] * invN;
    float var  = ssq[c] * invN - mean * mean;
    float sc   = g[c] * rsqrtf(var + EPS);
    scale[c] = sc;
    shift[c] = bt[c] - mean * sc;
}

// bn2 + relu + pool -> pool2 bf16 in fc1 B-frag order
// frag idx i = ((ks*32 + bt)*64 + lane)*8 + j
//   = pool2[b][k], b = bt*16 + (lane&15), k = ks*32 + (lane>>4)*8 + j; k = c*16 + psp
__global__ void k_bnpool2(const float* __restrict__ A, const float* __restrict__ scale,
                          const float* __restrict__ shift, unsigned short* __restrict__ xfrag) {
    int i = blockIdx.x * 256 + threadIdx.x;        // 1048576
    int j    = i & 7;
    int lane = (i >> 3) & 63;
    int bt   = (i >> 9) & 31;
    int ks   = i >> 14;
    int b = bt * 16 + (lane & 15);
    int k = ks * 32 + (lane >> 4) * 8 + j;
    int c = k >> 4, psp = k & 15;
    int ph = psp >> 2, pw = psp & 3;
    const float* xp = A + ((size_t)b * 128 + c) * 64 + ph * 16 + pw * 2;
    float sc = scale[c], sh = shift[c];
    float v0 = fmaxf(0.f, fmaf(xp[0], sc, sh));
    float v1 = fmaxf(0.f, fmaf(xp[1], sc, sh));
    float v2 = fmaxf(0.f, fmaf(xp[8], sc, sh));
    float v3 = fmaxf(0.f, fmaf(xp[9], sc, sh));
    xfrag[i] = f2bf(fmaxf(fmaxf(v0, v1), fmaxf(v2, v3)));
}

// fc1 MFMA: [512f x 2048k] x [512b x 2048k]^T -> out fp32 [b][f], fused bn3 stats.
// Grid 64: blockIdx = (btile8 <<3 | ftile8). Wave = one 16-b tile; 4 f-tiles.
__global__ __launch_bounds__(256) void k_fc1(const unsigned short* __restrict__ xfrag,
                                             const unsigned short* __restrict__ wfrag,
                                             float* __restrict__ out,
                                             float* __restrict__ sum,
                                             float* __restrict__ ssq) {
    int lane = threadIdx.x & 63;
    int wave = threadIdx.x >> 6;
    int fB = (blockIdx.x & 7) * 4;                 // f-tile base (16-f tiles)
    int bT = (blockIdx.x >> 3) * 4 + wave;         // b-tile (16 b)
    v4f acc[4];
    #pragma unroll
    for (int mt = 0; mt < 4; ++mt) acc[mt] = (v4f){0.f, 0.f, 0.f, 0.f};
    for (int ks = 0; ks < 64; ++ks) {
        v8s bfrag = *(const v8s*)(xfrag + ((size_t)(ks * 32 + bT) * 64 + lane) * 8);
        #pragma unroll
        for (int mt = 0; mt < 4; ++mt) {
            v8s afrag = *(const v8s*)(wfrag + ((size_t)(ks * 32 + fB + mt) * 64 + lane) * 8);
            acc[mt] = __builtin_amdgcn_mfma_f32_16x16x32_bf16(afrag, bfrag, acc[mt], 0, 0, 0);
        }
    }
    int bb = bT * 16 + (lane & 15);
    int quad = lane >> 4;
    #pragma unroll
    for (int mt = 0; mt < 4; ++mt) {
        int f0 = (fB + mt) * 16 + quad * 4;
        *(float4*)(&out[(size_t)bb * 512 + f0]) =
            make_float4(acc[mt][0], acc[mt][1], acc[mt][2], acc[mt][3]);
        #pragma unroll
        for (int r = 0; r < 4; ++r) {
            float s = acc[mt][r], s2 = s * s;
            #pragma unroll
            for (int m = 1; m < 16; m <<= 1) { s += __shfl_xor(s, m); s2 += __shfl_xor(s2, m); }
            if ((lane & 15) == 0) { atomicAdd(&sum[f0 + r], s); atomicAdd(&ssq[f0 + r], s2); }
        }
    }
}

__global__ void k_fcbn(float* __restrict__ x, const float* __restrict__ scale,
                       const float* __restrict__ shift) {
    int i = blockIdx.x * 256 + threadIdx.x;        // 262144
    int f = i & 511;
    x[i] = fmaxf(0.f, fmaf(x[i], scale[f], shift[f]));
}

// fc2: x[512,512] @ w[10,512]^T + b -> out[512,10]
__global__ void k_fc2(const float* __restrict__ x, const float* __restrict__ w,
                      const float* __restrict__ bias, float* __restrict__ out) {
    int idx = blockIdx.x * blockDim.x + threadIdx.x;
    if (idx >= 5120) return;
    int j = idx % 10; int b = idx / 10;
    const float* xp = x + (size_t)b * 512;
    const float* wp = w + j * 512;
    float acc = bias[j];
    #pragma unroll 4
    for (int k = 0; k < 512; ++k) acc = fmaf(wp[k], xp[k], acc);
    out[idx] = acc;
}

extern "C" void kernel_launch(void* const* d_in, const int* in_sizes, int n_in,
                              void* d_out, int out_size, void* d_ws, size_t ws_size,
                              hipStream_t stream) {
    const float* x       = (const float*)d_in[0];
    const float* conv1_w = (const float*)d_in[1];
    const float* bn1_g   = (const float*)d_in[3];
    const float* bn1_b   = (const float*)d_in[4];
    const float* conv2_w = (const float*)d_in[5];
    const float* bn2_g   = (const float*)d_in[7];
    const float* bn2_b   = (const float*)d_in[8];
    const float* fc1_w   = (const float*)d_in[9];
    const float* bn3_g   = (const float*)d_in[11];
    const float* bn3_b   = (const float*)d_in[12];
    const float* fc2_w   = (const float*)d_in[13];
    const float* fc2_b   = (const float*)d_in[14];
    // conv1_b / conv2_b / fc1_b are absorbed by train-mode BN

    float* wsf = (float*)d_ws;

    float* c1_sum = wsf + 16,   * c1_ssq = wsf + 80;
    float* c1_sc  = wsf + 144,  * c1_sh  = wsf + 208;
    float* c2_sum = wsf + 272,  * c2_ssq = wsf + 400;
    float* c2_sc  = wsf + 528,  * c2_sh  = wsf + 656;
    float* f_sc   = wsf + 784,  * f_sh   = wsf + 1296;
    float* f_sum  = wsf + 1808, * f_ssq  = wsf + 2320;

    float* w1t = wsf + W1F;
    unsigned short* w2u = (unsigned short*)(wsf + W2F);
    float* wf2 = wsf + WF2F;
    unsigned short* wf1 = (unsigned short*)(wsf + WF1T);
    float* A   = wsf + A_F;
    unsigned short* pool1 = (unsigned short*)(wsf + B_F);
    unsigned short* xfrag = (unsigned short*)(wsf + B_F);

    // zero stats (absmax + all sums)
    k_zero<<<16, 256, 0, stream>>>(wsf, 4096);

    // absmax (all 4 tensors)
    k_absmax4<<<82, 256, 0, stream>>>(conv1_w, 1600, conv2_w, 204800,
                                      fc1_w, 1048576, fc2_w, 5120, wsf);

    // quantize conv1 / conv2 (MFMA-frag bf16) / fc2
    k_quantE<<<102, 256, 0, stream>>>(conv1_w, conv2_w, fc2_w, wsf, w1t, w2u, wf2);

    // conv1 pass A: stats only
    k_conv1A<<<512, 512, 0, stream>>>(x, w1t, c1_sum, c1_ssq);
    k_finalize<<<1, 64, 0, stream>>>(c1_sum, c1_ssq, bn1_g, bn1_b, c1_sc, c1_sh, 64,
                                     1.f / 294912.f);

    // conv1 pass B: recompute + bn + relu + pool -> pool1 NHWC bf16
    k_conv1B<<<512, 512, 0, stream>>>(x, w1t, c1_sc, c1_sh, pool1);

    // conv2 MFMA (full K, fused bn2 stats) -> A fp32 [512,128,8,8]
    k_conv2<<<512, 256, 0, stream>>>(pool1, w2u, A, c2_sum, c2_ssq);

    // fc1 weights -> bf16 A-frag (pool1 now dead); exactly 1048576 threads
    k_quantF1<<<4096, 256, 0, stream>>>(fc1_w, wsf, wf1);

    k_finalize<<<1, 128, 0, stream>>>(c2_sum, c2_ssq, bn2_g, bn2_b, c2_sc, c2_sh, 128,
                                      1.f / 32768.f);

    // bn2+relu+pool -> pool2 bf16 B-frag
    k_bnpool2<<<4096, 256, 0, stream>>>(A, c2_sc, c2_sh, xfrag);

    // fc1 MFMA (fused bn3 stats) -> A fp32 [512,512]
    k_fc1<<<64, 256, 0, stream>>>(xfrag, wf1, A, f_sum, f_ssq);
    k_finalize<<<2, 256, 0, stream>>>(f_sum, f_ssq, bn3_g, bn3_b, f_sc, f_sh, 512,
                                      1.f / 512.f);

    // in-place bn3+relu on A
    k_fcbn<<<1024, 256, 0, stream>>>(A, f_sc, f_sh);

    // fc2 -> d_out [512,10]
    k_fc2<<<20, 256, 0, stream>>>(A, wf2, fc2_b, (float*)d_out);
}

// Round 7
// 248.460 us; speedup vs baseline: 7.2300x; 1.1203x over previous
//
#include <hip/hip_runtime.h>
#include <stdint.h>

#define EPS 1e-5f

typedef short v8s __attribute__((ext_vector_type(8)));
typedef float v4f __attribute__((ext_vector_type(4)));

// ---------------- ws float layout ----------------
//  [0,4)     absmax {c1,c2,f1,f2}
//  16/80/144/208    c1 sum/ssq/scale/shift (64 each)
//  272/400/528/656  c2 sum/ssq/scale/shift (128 each)
//  784 fc scale(512) 1296 fc shift(512)  1808 fc sum(512) 2320 fc ssq(512)
//  W1F  = 4096    : conv1 weights float [k=25][c=64]        (1600 f)
//  W2F  = 8192    : conv2 weights bf16 MFMA-frag order      (204800 us)
//  WF2F = 212992  : fc2 weights float [j][512]              (5120 f)
//  A_F  = 262144  : PMN fp32 [512][128][16][2]{max,min} (2097152 f),
//                   later fc1out fp32 [512,512] (256K f, PMN dead)
//  B_F  = 19136512: pool1 bf16 NHWC [512][144][64];
//                   later pool2 bf16 B-frag (1048576 us, pool1 dead)
//  WF1T = B_F + 1048576 : fc1 weights bf16 A-frag (1048576 us)
//         overlaps pool1 tail; written AFTER conv2 when pool1 is dead
static const size_t W1F  = 4096;
static const size_t W2F  = 8192;
static const size_t WF2F = 212992;
static const size_t A_F  = 262144;
static const size_t B_F  = 19136512;
static const size_t WF1T = B_F + 1048576;

__device__ inline unsigned short f2bf(float f) {
    unsigned u = __float_as_uint(f);
    return (unsigned short)((u + 0x7FFF + ((u >> 16) & 1)) >> 16);
}

// async global->LDS, 16B per lane; LDS dest = wave-uniform base + lane*16
__device__ __forceinline__ void stage16(const unsigned short* g, unsigned short* l) {
    __builtin_amdgcn_global_load_lds(
        (const __attribute__((address_space(1))) unsigned int*)g,
        (__attribute__((address_space(3))) unsigned int*)l, 16, 0, 0);
}

__global__ void k_zero(float* p, int n) {
    int i = blockIdx.x * blockDim.x + threadIdx.x;
    if (i < n) p[i] = 0.f;
}

// 4 absmax reductions in one launch (fc1_w gets 192 blocks)
__global__ void k_absmax4(const float* __restrict__ w0, int n0,
                          const float* __restrict__ w1, int n1,
                          const float* __restrict__ w2, int n2,
                          const float* __restrict__ w3, int n3,
                          float* outv) {
    int blk = blockIdx.x;
    const float* w; int n; unsigned* out; int nb; int bi;
    if (blk < 1)        { w = w0; n = n0; out = (unsigned*)(outv + 0); nb = 1;   bi = blk;      }
    else if (blk < 17)  { w = w1; n = n1; out = (unsigned*)(outv + 1); nb = 16;  bi = blk - 1;  }
    else if (blk < 209) { w = w2; n = n2; out = (unsigned*)(outv + 2); nb = 192; bi = blk - 17; }
    else                { w = w3; n = n3; out = (unsigned*)(outv + 3); nb = 1;   bi = blk - 209; }
    float m = 0.f;
    for (int i = bi * 256 + threadIdx.x; i < n; i += nb * 256)
        m = fmaxf(m, fabsf(w[i]));
    #pragma unroll
    for (int o = 32; o; o >>= 1) m = fmaxf(m, __shfl_down(m, o));
    if ((threadIdx.x & 63) == 0) atomicMax(out, __float_as_uint(m));
}

// quantize: conv1 -> w1t float [k=25][c=64]; conv2 -> bf16 A-frag order; fc2 float
// conv2 frag: idx = ((p*2+ks)*8 + mt)*512 + lane*8 + j
//   = Q(conv2_w[c][ci][p]), c = mt*16 + (lane&15), ci = ks*32 + (lane>>4)*8 + j
__global__ void k_quantE(const float* __restrict__ c1w, const float* __restrict__ c2w,
                         const float* __restrict__ f2w, const float* __restrict__ am,
                         float* __restrict__ w1t, unsigned short* __restrict__ w2u,
                         float* __restrict__ wf2) {
    int blk = blockIdx.x;
    if (blk < 1) {
        float t = 0.05f * am[0];
        for (int i = threadIdx.x; i < 1600; i += 256) {
            float v = c1w[i];
            float q = (float)((v > t) - (v < -t));
            int c = i / 25, k = i - c * 25;
            w1t[k * 64 + c] = q;
        }
    } else if (blk < 101) {
        float t = 0.05f * am[1];
        int base = (blk - 1) * 2048;
        #pragma unroll
        for (int jj = 0; jj < 8; ++jj) {
            int i = base + jj * 256 + threadIdx.x;
            int j    = i & 7;
            int lane = (i >> 3) & 63;
            int mt   = (i >> 9) & 7;
            int ks   = (i >> 12) & 1;
            int p    = i >> 13;
            int c  = mt * 16 + (lane & 15);
            int ci = ks * 32 + (lane >> 4) * 8 + j;
            float v = c2w[c * 1600 + ci * 25 + p];
            w2u[i] = (v > t) ? (unsigned short)0x3F80
                             : ((v < -t) ? (unsigned short)0xBF80 : (unsigned short)0);
        }
    } else {
        float t = 0.05f * am[3];
        for (int i = threadIdx.x; i < 5120; i += 256) {
            float v = f2w[i];
            wf2[i] = (float)((v > t) - (v < -t));
        }
    }
}

// fc1 quantize -> bf16 A-frag: idx = ((ks*32 + ft)*64 + lane)*8 + j
//   = Q(fc1_w[f][k]), f = ft*16 + (lane&15), k = ks*32 + (lane>>4)*8 + j
// exactly 1048576 threads
__global__ void k_quantF1(const float* __restrict__ w, const float* __restrict__ am,
                          unsigned short* __restrict__ wf) {
    float t = 0.05f * am[2];
    int i = blockIdx.x * 256 + threadIdx.x;
    int j    = i & 7;
    int lane = (i >> 3) & 63;
    int ft   = (i >> 9) & 31;
    int ks   = i >> 14;
    int f = ft * 16 + (lane & 15);
    int k = ks * 32 + (lane >> 4) * 8 + j;
    float v = w[f * 2048 + k];
    wf[i] = (v > t) ? (unsigned short)0x3F80
                    : ((v < -t) ? (unsigned short)0xBF80 : (unsigned short)0);
}

// conv1 pass A: stats only. Block per image, 512 threads; lane = out channel.
__global__ __launch_bounds__(512) void k_conv1A(const float* __restrict__ x,
                                                const float* __restrict__ w1t,
                                                float* __restrict__ sum,
                                                float* __restrict__ ssq) {
    __shared__ float xs[784];
    __shared__ float red[2][8][64];
    int b = blockIdx.x;
    const float4* xim = (const float4*)(x + (size_t)b * 784);
    for (int i = threadIdx.x; i < 196; i += 512) ((float4*)xs)[i] = xim[i];
    int c  = threadIdx.x & 63;
    int wv = threadIdx.x >> 6;
    float w[25];
    #pragma unroll
    for (int k = 0; k < 25; ++k) w[k] = w1t[k * 64 + c];
    __syncthreads();
    float s = 0.f, s2 = 0.f;
    int oh = 0, ow = wv;
    for (int it = 0; it < 72; ++it) {
        const float* xp = xs + oh * 28 + ow;
        float acc = 0.f;
        #pragma unroll
        for (int kh = 0; kh < 5; ++kh)
            #pragma unroll
            for (int kw = 0; kw < 5; ++kw)
                acc = fmaf(xp[kh * 28 + kw], w[kh * 5 + kw], acc);
        s += acc; s2 += acc * acc;
        ow += 8; if (ow >= 24) { ow -= 24; ++oh; }
    }
    red[0][wv][c] = s; red[1][wv][c] = s2;
    __syncthreads();
    if (threadIdx.x < 64) {
        float S = 0.f, S2 = 0.f;
        #pragma unroll
        for (int i = 0; i < 8; ++i) { S += red[0][i][threadIdx.x]; S2 += red[1][i][threadIdx.x]; }
        atomicAdd(&sum[threadIdx.x], S);
        atomicAdd(&ssq[threadIdx.x], S2);
    }
}

// conv1 pass B: recompute conv1 + bn + relu + pool -> pool1 NHWC bf16 [b][144][64]
__global__ __launch_bounds__(512) void k_conv1B(const float* __restrict__ x,
                                                const float* __restrict__ w1t,
                                                const float* __restrict__ scale,
                                                const float* __restrict__ shift,
                                                unsigned short* __restrict__ pool1) {
    __shared__ float xs[784];
    int b = blockIdx.x;
    const float4* xim = (const float4*)(x + (size_t)b * 784);
    for (int i = threadIdx.x; i < 196; i += 512) ((float4*)xs)[i] = xim[i];
    int c  = threadIdx.x & 63;
    int wv = threadIdx.x >> 6;
    float w[25];
    #pragma unroll
    for (int k = 0; k < 25; ++k) w[k] = w1t[k * 64 + c];
    float sc = scale[c], sh = shift[c];
    __syncthreads();
    unsigned short* ob = pool1 + (size_t)b * 9216;
    int ph = 0, pw = wv;
    for (int it = 0; it < 18; ++it) {
        const float* xp = xs + (ph * 2) * 28 + pw * 2;
        float win[36];
        #pragma unroll
        for (int i = 0; i < 6; ++i)
            #pragma unroll
            for (int j = 0; j < 6; ++j) win[i * 6 + j] = xp[i * 28 + j];
        float v00 = 0.f, v01 = 0.f, v10 = 0.f, v11 = 0.f;
        #pragma unroll
        for (int i = 0; i < 5; ++i)
            #pragma unroll
            for (int j = 0; j < 5; ++j) {
                float wk = w[i * 5 + j];
                v00 = fmaf(win[i * 6 + j],           wk, v00);
                v01 = fmaf(win[i * 6 + j + 1],       wk, v01);
                v10 = fmaf(win[(i + 1) * 6 + j],     wk, v10);
                v11 = fmaf(win[(i + 1) * 6 + j + 1], wk, v11);
            }
        float r0 = fmaxf(0.f, fmaf(v00, sc, sh));
        float r1 = fmaxf(0.f, fmaf(v01, sc, sh));
        float r2 = fmaxf(0.f, fmaf(v10, sc, sh));
        float r3 = fmaxf(0.f, fmaf(v11, sc, sh));
        ob[(ph * 12 + pw) * 64 + c] = f2bf(fmaxf(fmaxf(r0, r1), fmaxf(r2, r3)));
        pw += 8; if (pw >= 12) { pw -= 12; ++ph; }
    }
}

// conv2 MFMA v3: LDS-dbuf weight tiles (global_load_lds w16), 2x2 wave split,
// fused bn2 stats + fused 2x2 maxpool (stores {max,min} pairs; full-res output
// never materialized). Block per image; wave = (mhalf, nhalf).
__global__ __launch_bounds__(256) void k_conv2(const unsigned short* __restrict__ pool1,
                                               const unsigned short* __restrict__ wfrag,
                                               float* __restrict__ pmn,
                                               float* __restrict__ sum,
                                               float* __restrict__ ssq) {
    __shared__ unsigned short xs[10368];       // act, ldci = 72
    __shared__ unsigned short wb[2][4096];     // 2 x 8KB weight tiles
    __shared__ float reds[2][128], redq[2][128];
    int b    = blockIdx.x;
    int tid  = threadIdx.x;
    int lane = tid & 63;
    int wave = tid >> 6;
    const unsigned short* src = pool1 + (size_t)b * 9216;
    for (int i = tid; i < 1152; i += 256) {
        int r = i >> 3, part = i & 7;
        *(float4*)(&xs[r * 72 + part * 8]) = *(const float4*)(src + r * 64 + part * 8);
    }
    {   // prefetch tile 0
        const unsigned short* g = wfrag + wave * 512 + lane * 8;
        stage16(g,        &wb[0][wave * 512 + lane * 8]);
        stage16(g + 2048, &wb[0][2048 + wave * 512 + lane * 8]);
    }
    __syncthreads();

    int mh = wave >> 1, nh = wave & 1;
    int n = lane & 15, quad = lane >> 4;
    int ow = n & 7;
    int ohb0 = nh * 4 + (n >> 3);              // oh of bf0; bf1 = +2
    int cib  = quad * 8;
    v4f acc[4][2];
    #pragma unroll
    for (int mm = 0; mm < 4; ++mm) { acc[mm][0] = (v4f){0,0,0,0}; acc[mm][1] = (v4f){0,0,0,0}; }
    int kh = 0, kw = 0;
    for (int step = 0; step < 50; ++step) {
        int cur = step & 1;
        if (step < 49) {
            const unsigned short* g = wfrag + (size_t)(step + 1) * 4096 + wave * 512 + lane * 8;
            stage16(g,        &wb[cur ^ 1][wave * 512 + lane * 8]);
            stage16(g + 2048, &wb[cur ^ 1][2048 + wave * 512 + lane * 8]);
        }
        int ks = step & 1;
        int col = (ow + kw) * 72 + ks * 32 + cib;
        v8s bf0 = *(const v8s*)(&xs[(ohb0 + kh) * 864 + col]);       // 12*72=864
        v8s bf1 = *(const v8s*)(&xs[(ohb0 + 2 + kh) * 864 + col]);
        #pragma unroll
        for (int mm = 0; mm < 4; ++mm) {
            v8s af = *(const v8s*)(&wb[cur][(mh * 4 + mm) * 512 + lane * 8]);
            acc[mm][0] = __builtin_amdgcn_mfma_f32_16x16x32_bf16(af, bf0, acc[mm][0], 0, 0, 0);
            acc[mm][1] = __builtin_amdgcn_mfma_f32_16x16x32_bf16(af, bf1, acc[mm][1], 0, 0, 0);
        }
        if (ks) { ++kw; if (kw == 5) { kw = 0; ++kh; } }
        __syncthreads();
    }
    // epilogue: per-channel stats (pre-pool) + pooled {max,min}
    float* po = pmn + (size_t)b * 4096;        // [128][16][2]
    #pragma unroll
    for (int mm = 0; mm < 4; ++mm) {
        int c0 = (mh * 4 + mm) * 16 + quad * 4;
        #pragma unroll
        for (int r = 0; r < 4; ++r) {
            int c = c0 + r;
            float sA = 0.f, s2A = 0.f;
            #pragma unroll
            for (int bf = 0; bf < 2; ++bf) {
                float v = acc[mm][bf][r];
                float pm = fmaxf(v, __shfl_xor(v, 1));
                float pn = fminf(v, __shfl_xor(v, 1));
                pm = fmaxf(pm, __shfl_xor(pm, 8));
                pn = fminf(pn, __shfl_xor(pn, 8));
                if ((n & 9) == 0 || (n & 9) == 8) { /* unused guard form */ }
                if (((n & 1) == 0) && (n < 8)) {
                    int psp = (nh * 2 + bf) * 4 + (n >> 1);
                    *(float2*)(&po[(c * 16 + psp) * 2]) = make_float2(pm, pn);
                }
                float s = v, s2 = v * v;
                #pragma unroll
                for (int m = 1; m < 16; m <<= 1) { s += __shfl_xor(s, m); s2 += __shfl_xor(s2, m); }
                sA += s; s2A += s2;
            }
            if (n == 0) { reds[nh][c] = sA; redq[nh][c] = s2A; }
        }
    }
    __syncthreads();
    if (tid < 128) {
        atomicAdd(&sum[tid], reds[0][tid] + reds[1][tid]);
        atomicAdd(&ssq[tid], redq[0][tid] + redq[1][tid]);
    }
}

__global__ void k_finalize(const float* __restrict__ sum, const float* __restrict__ ssq,
                           const float* __restrict__ g, const float* __restrict__ bt,
                           float* __restrict__ scale, float* __restrict__ shift,
                           int C, float invN) {
    int c = blockIdx.x * blockDim.x + threadIdx.x;
    if (c >= C) return;
    float mean = sum[c] * invN;
    float var  = ssq[c] * invN - mean * mean;
    float sc   = g[c] * rsqrtf(var + EPS);
    scale[c] = sc;
    shift[c] = bt[c] - mean * sc;
}

// bn2+relu on pooled pairs -> pool2 bf16 in fc1 B-frag order
// pool(relu(aff(v))) = relu(aff(sc>0 ? max : min))
__global__ void k_bnpool2(const float* __restrict__ pmn, const float* __restrict__ scale,
                          const float* __restrict__ shift, unsigned short* __restrict__ xfrag) {
    int i = blockIdx.x * 256 + threadIdx.x;    // 1048576
    int j    = i & 7;
    int lane = (i >> 3) & 63;
    int bt   = (i >> 9) & 31;
    int ks   = i >> 14;
    int b = bt * 16 + (lane & 15);
    int k = ks * 32 + (lane >> 4) * 8 + j;
    int c = k >> 4, psp = k & 15;
    float2 mm = *(const float2*)(&pmn[((size_t)b * 2048 + c * 16 + psp) * 2]);
    float sc = scale[c], sh = shift[c];
    float v = (sc > 0.f) ? mm.x : mm.y;
    xfrag[i] = f2bf(fmaxf(0.f, fmaf(v, sc, sh)));
}

// fc1 MFMA: [512f x 2048k] x [512b x 2048k]^T -> out fp32 [b][f], fused bn3 stats.
// Grid 128: blockIdx = bT*4 + ftg; wave -> 2 f-tiles.
__global__ __launch_bounds__(256) void k_fc1(const unsigned short* __restrict__ xfrag,
                                             const unsigned short* __restrict__ wfrag,
                                             float* __restrict__ out,
                                             float* __restrict__ sum,
                                             float* __restrict__ ssq) {
    int lane = threadIdx.x & 63;
    int wave = threadIdx.x >> 6;
    int fB = (blockIdx.x & 3) * 8 + wave * 2;
    int bT = blockIdx.x >> 2;
    v4f acc[2];
    acc[0] = (v4f){0,0,0,0}; acc[1] = (v4f){0,0,0,0};
    for (int ks = 0; ks < 64; ++ks) {
        v8s bfrag = *(const v8s*)(xfrag + ((size_t)(ks * 32 + bT) * 64 + lane) * 8);
        #pragma unroll
        for (int mt = 0; mt < 2; ++mt) {
            v8s afrag = *(const v8s*)(wfrag + ((size_t)(ks * 32 + fB + mt) * 64 + lane) * 8);
            acc[mt] = __builtin_amdgcn_mfma_f32_16x16x32_bf16(afrag, bfrag, acc[mt], 0, 0, 0);
        }
    }
    int bb = bT * 16 + (lane & 15);
    int quad = lane >> 4;
    #pragma unroll
    for (int mt = 0; mt < 2; ++mt) {
        int f0 = (fB + mt) * 16 + quad * 4;
        *(float4*)(&out[(size_t)bb * 512 + f0]) =
            make_float4(acc[mt][0], acc[mt][1], acc[mt][2], acc[mt][3]);
        #pragma unroll
        for (int r = 0; r < 4; ++r) {
            float s = acc[mt][r], s2 = s * s;
            #pragma unroll
            for (int m = 1; m < 16; m <<= 1) { s += __shfl_xor(s, m); s2 += __shfl_xor(s2, m); }
            if ((lane & 15) == 0) { atomicAdd(&sum[f0 + r], s); atomicAdd(&ssq[f0 + r], s2); }
        }
    }
}

// fc2 with fused bn3+relu: wave per batch row; lane-parallel float4 loads.
__global__ __launch_bounds__(256) void k_fc2(const float* __restrict__ x,
                                             const float* __restrict__ w,
                                             const float* __restrict__ bias,
                                             const float* __restrict__ scale,
                                             const float* __restrict__ shift,
                                             float* __restrict__ out) {
    int lane = threadIdx.x & 63;
    int b = blockIdx.x * 4 + (threadIdx.x >> 6);
    const float4* xp = (const float4*)(x + (size_t)b * 512 + lane * 8);
    const float4* scp = (const float4*)(scale + lane * 8);
    const float4* shp = (const float4*)(shift + lane * 8);
    float4 x0 = xp[0], x1 = xp[1];
    float4 s0 = scp[0], s1 = scp[1];
    float4 h0 = shp[0], h1 = shp[1];
    float h[8];
    h[0] = fmaxf(0.f, fmaf(x0.x, s0.x, h0.x));
    h[1] = fmaxf(0.f, fmaf(x0.y, s0.y, h0.y));
    h[2] = fmaxf(0.f, fmaf(x0.z, s0.z, h0.z));
    h[3] = fmaxf(0.f, fmaf(x0.w, s0.w, h0.w));
    h[4] = fmaxf(0.f, fmaf(x1.x, s1.x, h1.x));
    h[5] = fmaxf(0.f, fmaf(x1.y, s1.y, h1.y));
    h[6] = fmaxf(0.f, fmaf(x1.z, s1.z, h1.z));
    h[7] = fmaxf(0.f, fmaf(x1.w, s1.w, h1.w));
    #pragma unroll
    for (int j = 0; j < 10; ++j) {
        const float4* wp = (const float4*)(w + j * 512 + lane * 8);
        float4 w0 = wp[0], w1 = wp[1];
        float p = h[0] * w0.x + h[1] * w0.y + h[2] * w0.z + h[3] * w0.w
                + h[4] * w1.x + h[5] * w1.y + h[6] * w1.z + h[7] * w1.w;
        #pragma unroll
        for (int o = 32; o; o >>= 1) p += __shfl_down(p, o);
        if (lane == 0) out[b * 10 + j] = p + bias[j];
    }
}

extern "C" void kernel_launch(void* const* d_in, const int* in_sizes, int n_in,
                              void* d_out, int out_size, void* d_ws, size_t ws_size,
                              hipStream_t stream) {
    const float* x       = (const float*)d_in[0];
    const float* conv1_w = (const float*)d_in[1];
    const float* bn1_g   = (const float*)d_in[3];
    const float* bn1_b   = (const float*)d_in[4];
    const float* conv2_w = (const float*)d_in[5];
    const float* bn2_g   = (const float*)d_in[7];
    const float* bn2_b   = (const float*)d_in[8];
    const float* fc1_w   = (const float*)d_in[9];
    const float* bn3_g   = (const float*)d_in[11];
    const float* bn3_b   = (const float*)d_in[12];
    const float* fc2_w   = (const float*)d_in[13];
    const float* fc2_b   = (const float*)d_in[14];
    // conv1_b / conv2_b / fc1_b are absorbed by train-mode BN

    float* wsf = (float*)d_ws;

    float* c1_sum = wsf + 16,   * c1_ssq = wsf + 80;
    float* c1_sc  = wsf + 144,  * c1_sh  = wsf + 208;
    float* c2_sum = wsf + 272,  * c2_ssq = wsf + 400;
    float* c2_sc  = wsf + 528,  * c2_sh  = wsf + 656;
    float* f_sc   = wsf + 784,  * f_sh   = wsf + 1296;
    float* f_sum  = wsf + 1808, * f_ssq  = wsf + 2320;

    float* w1t = wsf + W1F;
    unsigned short* w2u = (unsigned short*)(wsf + W2F);
    float* wf2 = wsf + WF2F;
    unsigned short* wf1 = (unsigned short*)(wsf + WF1T);
    float* PMN = wsf + A_F;                          // [512][128][16][2]
    float* A   = wsf + A_F;                          // fc1out (PMN dead by then)
    unsigned short* pool1 = (unsigned short*)(wsf + B_F);
    unsigned short* xfrag = (unsigned short*)(wsf + B_F);

    // zero stats (absmax + all sums)
    k_zero<<<16, 256, 0, stream>>>(wsf, 4096);

    // absmax (all 4 tensors)
    k_absmax4<<<210, 256, 0, stream>>>(conv1_w, 1600, conv2_w, 204800,
                                       fc1_w, 1048576, fc2_w, 5120, wsf);

    // quantize conv1 / conv2 (MFMA-frag bf16) / fc2
    k_quantE<<<102, 256, 0, stream>>>(conv1_w, conv2_w, fc2_w, wsf, w1t, w2u, wf2);

    // conv1 pass A: stats only
    k_conv1A<<<512, 512, 0, stream>>>(x, w1t, c1_sum, c1_ssq);
    k_finalize<<<1, 64, 0, stream>>>(c1_sum, c1_ssq, bn1_g, bn1_b, c1_sc, c1_sh, 64,
                                     1.f / 294912.f);

    // conv1 pass B: recompute + bn + relu + pool -> pool1 NHWC bf16
    k_conv1B<<<512, 512, 0, stream>>>(x, w1t, c1_sc, c1_sh, pool1);

    // conv2 MFMA v3 (LDS weight dbuf, fused stats + pool-minmax) -> PMN
    k_conv2<<<512, 256, 0, stream>>>(pool1, w2u, PMN, c2_sum, c2_ssq);

    // fc1 weights -> bf16 A-frag (pool1 now dead)
    k_quantF1<<<4096, 256, 0, stream>>>(fc1_w, wsf, wf1);

    k_finalize<<<1, 128, 0, stream>>>(c2_sum, c2_ssq, bn2_g, bn2_b, c2_sc, c2_sh, 128,
                                      1.f / 32768.f);

    // bn2+relu on pooled pairs -> pool2 bf16 B-frag
    k_bnpool2<<<4096, 256, 0, stream>>>(PMN, c2_sc, c2_sh, xfrag);

    // fc1 MFMA (fused bn3 stats) -> A fp32 [512,512]
    k_fc1<<<128, 256, 0, stream>>>(xfrag, wf1, A, f_sum, f_ssq);
    k_finalize<<<2, 256, 0, stream>>>(f_sum, f_ssq, bn3_g, bn3_b, f_sc, f_sh, 512,
                                      1.f / 512.f);

    // fc2 (fused bn3+relu) -> d_out [512,10]
    k_fc2<<<128, 256, 0, stream>>>(A, wf2, fc2_b, f_sc, f_sh, (float*)d_out);
}